// Round 4
// baseline (18958.495 us; speedup 1.0000x reference)
//
#include <hip/hip_runtime.h>
#include <math.h>

#define B_  64
#define T_  2048
#define C_  256
#define H_  512
#define O_  256
#define NSTEP 2047

typedef __attribute__((ext_vector_type(8))) short short8x;
typedef __attribute__((ext_vector_type(4))) float f32x4;

__device__ __forceinline__ unsigned short f2bf_bits(float x){
  unsigned int u = __builtin_bit_cast(unsigned int, x);
  u = u + 0x7FFFu + ((u >> 16) & 1u);      // RNE
  return (unsigned short)(u >> 16);
}
__device__ __forceinline__ float bf2f(unsigned short h){
  unsigned int u = ((unsigned int)h) << 16;
  return __builtin_bit_cast(float, u);
}
__device__ __forceinline__ short8x pack8(float4 a, float4 b){
  short8x w;
  w[0]=(short)f2bf_bits(a.x); w[1]=(short)f2bf_bits(a.y);
  w[2]=(short)f2bf_bits(a.z); w[3]=(short)f2bf_bits(a.w);
  w[4]=(short)f2bf_bits(b.x); w[5]=(short)f2bf_bits(b.y);
  w[6]=(short)f2bf_bits(b.z); w[7]=(short)f2bf_bits(b.w);
  return w;
}
__device__ __forceinline__ f32x4 MFMA(short8x a, short8x b, f32x4 c){
  return __builtin_amdgcn_mfma_f32_16x16x32_bf16(a, b, c, 0, 0, 0);
}
__device__ __forceinline__ float softplus_f(float x){
  return (x > 20.f) ? x : log1pf(expf(x));
}
__device__ __forceinline__ float fast_exp2(float x){ return __builtin_amdgcn_exp2f(x); }
__device__ __forceinline__ float fast_rcp(float x){ return __builtin_amdgcn_rcpf(x); }
__device__ __forceinline__ float sigmoid_f(float x){
  return fast_rcp(1.f + fast_exp2(-1.44269504f * x));
}
__device__ __forceinline__ float tanh_f(float x){
  return 1.f - 2.f * fast_rcp(1.f + fast_exp2(2.88539008f * x));
}

// agent-scope ops: bypass stale L1/L2, hit the device coherence point (LLC).
__device__ __forceinline__ void st_agent_u16(unsigned short* p, unsigned short v){
  __hip_atomic_store(p, v, __ATOMIC_RELAXED, __HIP_MEMORY_SCOPE_AGENT);
}
__device__ __forceinline__ unsigned long long ld_agent_u64(unsigned long long* p){
  return __hip_atomic_load(p, __ATOMIC_RELAXED, __HIP_MEMORY_SCOPE_AGENT);
}

// any 16-bit field == 0xFFFF (sentinel = -NaN bf16, unreachable from finite math)
__device__ __forceinline__ int has_ffff(unsigned long long w){
  unsigned long long nv = ~w;
  return ((nv - 0x0001000100010001ull) & ~nv & 0x8000800080008000ull) != 0ull;
}
__device__ __forceinline__ float sq4(unsigned long long w){
  unsigned lo = (unsigned)w, hi = (unsigned)(w >> 32);
  float f0 = __builtin_bit_cast(float, lo << 16);
  float f1 = __builtin_bit_cast(float, lo & 0xFFFF0000u);
  float f2 = __builtin_bit_cast(float, hi << 16);
  float f3 = __builtin_bit_cast(float, hi & 0xFFFF0000u);
  return f0*f0 + f1*f1 + f2*f2 + f3*f3;
}

union ChunkU { short8x v; unsigned long long q[2]; };

// barrier with LDS-drain only (no vmcnt(0): do NOT serialize on store-ack)
__device__ __forceinline__ void barrier_lds(){
  asm volatile("s_waitcnt lgkmcnt(0)" ::: "memory");
  __builtin_amdgcn_s_barrier();
  asm volatile("" ::: "memory");
}

// hs layout: [t][g(4)][slice(16)][bb(16)][u(32)] bf16
// index(t,g,s,bb,u) = ((t*4+g)*8192) + s*512 + bb*32 + u   (in shorts)

// ---------------------------------------------------------------------------
// Init MLP -> hs[t=0] (pre-retract bf16).
// ---------------------------------------------------------------------------
__global__ void k_mlp(const float* __restrict__ cv,
                      const float* __restrict__ w0, const float* __restrict__ bb0,
                      const float* __restrict__ w1, const float* __restrict__ bb1,
                      const float* __restrict__ w2, const float* __restrict__ bb2,
                      unsigned short* __restrict__ hs)
{
  const int b = blockIdx.x, tid = threadIdx.x;
  const int wave = tid >> 6, lane = tid & 63;
  __shared__ float xr[256], a0[512], a1[512], a2[512];

  xr[tid] = cv[(size_t)b * T_ * C_ + tid];
  __syncthreads();

  for (int i = 0; i < 32; i++){
    float s[4];
    #pragma unroll
    for (int uu = 0; uu < 4; uu++){
      int j = wave*128 + i*4 + uu;
      const float4* wr = (const float4*)(w0 + (size_t)j * 256);
      float4 w = wr[lane];
      s[uu] = w.x*xr[lane*4+0] + w.y*xr[lane*4+1] + w.z*xr[lane*4+2] + w.w*xr[lane*4+3];
    }
    #pragma unroll
    for (int off = 32; off; off >>= 1){
      #pragma unroll
      for (int uu = 0; uu < 4; uu++) s[uu] += __shfl_xor(s[uu], off, 64);
    }
    if (lane < 4){ int j = wave*128 + i*4 + lane; a0[j] = softplus_f(s[lane] + bb0[j]); }
  }
  __syncthreads();

  for (int i = 0; i < 32; i++){
    float s[4];
    #pragma unroll
    for (int uu = 0; uu < 4; uu++){
      int j = wave*128 + i*4 + uu;
      const float4* wr = (const float4*)(w1 + (size_t)j * 512);
      float4 wA = wr[lane*2], wB = wr[lane*2+1];
      int k0 = lane*8;
      s[uu] = wA.x*a0[k0]   + wA.y*a0[k0+1] + wA.z*a0[k0+2] + wA.w*a0[k0+3]
            + wB.x*a0[k0+4] + wB.y*a0[k0+5] + wB.z*a0[k0+6] + wB.w*a0[k0+7];
    }
    #pragma unroll
    for (int off = 32; off; off >>= 1){
      #pragma unroll
      for (int uu = 0; uu < 4; uu++) s[uu] += __shfl_xor(s[uu], off, 64);
    }
    if (lane < 4){ int j = wave*128 + i*4 + lane; a1[j] = softplus_f(s[lane] + bb1[j]); }
  }
  __syncthreads();

  for (int i = 0; i < 32; i++){
    float s[4];
    #pragma unroll
    for (int uu = 0; uu < 4; uu++){
      int j = wave*128 + i*4 + uu;
      const float4* wr = (const float4*)(w2 + (size_t)j * 512);
      float4 wA = wr[lane*2], wB = wr[lane*2+1];
      int k0 = lane*8;
      s[uu] = wA.x*a1[k0]   + wA.y*a1[k0+1] + wA.z*a1[k0+2] + wA.w*a1[k0+3]
            + wB.x*a1[k0+4] + wB.y*a1[k0+5] + wB.z*a1[k0+6] + wB.w*a1[k0+7];
    }
    #pragma unroll
    for (int off = 32; off; off >>= 1){
      #pragma unroll
      for (int uu = 0; uu < 4; uu++) s[uu] += __shfl_xor(s[uu], off, 64);
    }
    if (lane < 4){ int j = wave*128 + i*4 + lane; a2[j] = s[lane] + bb2[j]; }
  }
  __syncthreads();

  const int g = b >> 4, bb = b & 15;
  {
    int u = tid;
    hs[(size_t)g*8192 + (u>>5)*512 + bb*32 + (u&31)] = f2bf_bits(a2[u]);
    u = tid + 256;
    hs[(size_t)g*8192 + (u>>5)*512 + bb*32 + (u&31)] = f2bf_bits(a2[u]);
  }
}

// ---------------------------------------------------------------------------
__global__ void k_wcvt(const float* __restrict__ w, unsigned short* __restrict__ o)
{
  int idx = blockIdx.x * 256 + threadIdx.x;
  if (idx < O_ * H_) o[idx] = f2bf_bits(w[idx]);
}

// ---------------------------------------------------------------------------
// Persistent GRU scan, v4: r3 protocol + cross-step prefetch everywhere.
//  - waves 0-2: first-pass tile loads issued at END of phase C of the PREVIOUS
//    step (plain cached); validated after the barrier; agent retry fallback.
//  - wave 3: cv(t+1) loads issued during phase A of step t (full step in flight).
//  - h_t published immediately after computation (flight starts earliest).
// 64 wgs = 4 batch-groups x 16 unit-slices.
// ---------------------------------------------------------------------------
__global__ __launch_bounds__(256, 1)
void k_scan(const float* __restrict__ cv, const float* __restrict__ w_ih,
            const float* __restrict__ w_hh, const float* __restrict__ bias,
            const float* __restrict__ b_n,
            unsigned short* __restrict__ hs, float* __restrict__ sumsq)
{
  const int wg   = blockIdx.x;
  const int g    = wg >> 4;         // batch group 0..3
  const int sidx = wg & 15;         // unit slice 0..15
  const int b0   = g * 16;
  const int u0   = sidx * 32;
  const int tid  = threadIdx.x;
  const int wave = tid >> 6, lane = tid & 63;
  const int lm   = lane & 15, quad = lane >> 4;
  const int gb   = tid >> 5;        // 0..7
  const int uu   = tid & 31;

  __shared__ float accLds[12][16][16];       // 0..5 hh (gate*2+nt), 6..11 ih
  __shared__ float ssqR[3][16];              // per-wave sumsq partials per batch
  __shared__ unsigned short tileOwn[512];    // own slice's h_{t-1} chunk (1 KiB)
  __shared__ float bias_lds[3][32];
  __shared__ float bn_lds[32];

  if (tid < 32){
    bias_lds[0][tid] = bias[u0 + tid];
    bias_lds[1][tid] = bias[512 + u0 + tid];
    bias_lds[2][tid] = bias[1024 + u0 + tid];
    bn_lds[tid]      = b_n[u0 + tid];
  }
  // own pre-retract h (fp32) in registers
  float hp0 = bf2f(hs[(size_t)g*8192 + sidx*512 + gb*32 + uu]);
  float hp1 = bf2f(hs[(size_t)g*8192 + sidx*512 + (gb+8)*32 + uu]);
  // stage own chunk of h_0 in LDS (consumed at t=1 phase A)
  tileOwn[gb*32 + uu]     = f2bf_bits(hp0);
  tileOwn[(gb+8)*32 + uu] = f2bf_bits(hp1);

  // ---- weight fragments in registers (bf16), loaded once ----
  short8x wreg[48];
  if (wave < 3){
    const int gate = wave;
    #pragma unroll
    for (int nt = 0; nt < 2; nt++){
      #pragma unroll
      for (int k = 0; k < 16; k++){
        const float* p = w_hh + ((size_t)(gate*512 + u0 + nt*16 + lm)) * 512 + k*32 + quad*8;
        wreg[nt*16 + k] = pack8(*(const float4*)p, *(const float4*)(p + 4));
      }
    }
  } else {
    #pragma unroll
    for (int g2 = 0; g2 < 3; g2++){
      #pragma unroll
      for (int nt = 0; nt < 2; nt++){
        #pragma unroll
        for (int kk = 0; kk < 8; kk++){
          const float* p = w_ih + ((size_t)(g2*512 + u0 + nt*16 + lm)) * 256 + kk*32 + quad*8;
          wreg[(g2*2 + nt)*8 + kk] = pack8(*(const float4*)p, *(const float4*)(p + 4));
        }
      }
    }
  }

  // ---- cross-step prefetch state ----
  ChunkU ch[16];        // waves 0-2: h tile (own chunk filled from LDS each step)
  float4 cvp[16];       // wave 3: cv row fragments for the upcoming step

  if (wave < 3){
    // first-pass loads of the t=0 tile (written by k_mlp, flushed at dispatch end)
    const unsigned short* hb = hs + (size_t)g*8192 + lm*32 + quad*8;
    #pragma unroll
    for (int k = 0; k < 16; k++)
      if (k != sidx) ch[k].v = *(const short8x*)(hb + (size_t)k*512);
  } else {
    // prefetch cv for t=1
    const size_t xbase = ((size_t)(b0 + lm) * T_ + 1) * C_;
    #pragma unroll
    for (int kk = 0; kk < 8; kk++){
      const float* xp = cv + xbase + kk*32 + quad*8;
      cvp[2*kk]   = *(const float4*)xp;
      cvp[2*kk+1] = *(const float4*)(xp + 4);
    }
  }
  __syncthreads();

  for (int t = 1; t <= NSTEP; t++){
    if (wave < 3){
      // ---- phase A: own chunk from LDS; validate prefetched tile ----
      ch[sidx].v = *(const short8x*)&tileOwn[lm*32 + quad*8];
      const unsigned short* hb = hs + ((size_t)(t-1)*4 + g)*8192 + lm*32 + quad*8;
      unsigned pend = 0xFFFFu & ~(1u << sidx);
      int spin = 0;
      for (;;){
        unsigned np = 0u;
        #pragma unroll
        for (int k = 0; k < 16; k++)
          if (((pend >> k) & 1u) && (has_ffff(ch[k].q[0]) | has_ffff(ch[k].q[1])))
            np |= 1u << k;
        if (!__any((int)np)) break;
        pend = np;
        if (spin++) __builtin_amdgcn_s_sleep(1);   // backoff: don't hammer the fabric
        #pragma unroll
        for (int k = 0; k < 16; k++)
          if ((pend >> k) & 1u){
            unsigned long long* p = (unsigned long long*)(hb + (size_t)k*512);
            ch[k].q[0] = ld_agent_u64(p);
            ch[k].q[1] = ld_agent_u64(p + 1);
          }
      }

      // ---- hh-GEMM from registers ----
      f32x4 acc0 = {0.f,0.f,0.f,0.f}, acc1 = {0.f,0.f,0.f,0.f};
      #pragma unroll
      for (int k = 0; k < 16; k++){
        acc0 = MFMA(ch[k].v, wreg[k],      acc0);
        acc1 = MFMA(ch[k].v, wreg[16 + k], acc1);
      }
      #pragma unroll
      for (int r = 0; r < 4; r++){
        accLds[wave*2 + 0][quad*4 + r][lm] = acc0[r];
        accLds[wave*2 + 1][quad*4 + r][lm] = acc1[r];
      }

      // ---- in-wave sumsq of h_{t-1} (k-ranges 6/5/5 across waves 0..2) ----
      const int klo = (wave == 0) ? 0 : (wave == 1 ? 6 : 11);
      const int khi = (wave == 0) ? 6 : (wave == 1 ? 11 : 16);
      float s = 0.f;
      #pragma unroll
      for (int k = 0; k < 16; k++){
        if (k >= klo && k < khi) s += sq4(ch[k].q[0]) + sq4(ch[k].q[1]);
      }
      s += __shfl_xor(s, 16, 64);   // reduce over the 4 quads of batch lm
      s += __shfl_xor(s, 32, 64);
      if (lane < 16) ssqR[wave][lane] = s;
    } else {
      // ---- ih GEMM from prefetched cv registers ----
      short8x af[8];
      #pragma unroll
      for (int kk = 0; kk < 8; kk++) af[kk] = pack8(cvp[2*kk], cvp[2*kk+1]);
      f32x4 acc[6];
      #pragma unroll
      for (int tt = 0; tt < 6; tt++) acc[tt] = (f32x4){0.f,0.f,0.f,0.f};
      #pragma unroll
      for (int kk = 0; kk < 8; kk++){
        #pragma unroll
        for (int tt = 0; tt < 6; tt++) acc[tt] = MFMA(af[kk], wreg[tt*8 + kk], acc[tt]);
      }
      #pragma unroll
      for (int tt = 0; tt < 6; tt++){
        #pragma unroll
        for (int r = 0; r < 4; r++) accLds[6 + tt][quad*4 + r][lm] = acc[tt][r];
      }
      // issue cv prefetch for t+1 (full step of latency hiding)
      if (t < NSTEP){
        const size_t xbase = ((size_t)(b0 + lm) * T_ + (t+1)) * C_;
        #pragma unroll
        for (int kk = 0; kk < 8; kk++){
          const float* xp = cv + xbase + kk*32 + quad*8;
          cvp[2*kk]   = *(const float4*)xp;
          cvp[2*kk+1] = *(const float4*)(xp + 4);
        }
      }
    }
    barrier_lds();

    // ---------------- gate phase (all 256 threads, 2 elems each) ----------------
    const float s0 = ssqR[0][gb]   + ssqR[1][gb]   + ssqR[2][gb];
    const float s1 = ssqR[0][gb+8] + ssqR[1][gb+8] + ssqR[2][gb+8];
    if (sidx == 0 && uu == 0){
      sumsq[(size_t)(t-1)*64 + b0 + gb]     = s0;
      sumsq[(size_t)(t-1)*64 + b0 + gb + 8] = s1;
    }
    const int nt = uu >> 4, ul = uu & 15;
    float hnew0, hnew1;
    {
      const float sp = rsqrtf(s0 + 1e-12f);
      float rv = accLds[6 + 0 + nt][gb][ul] + bias_lds[0][uu] + sp*accLds[0 + nt][gb][ul];
      float zv = accLds[6 + 2 + nt][gb][ul] + bias_lds[1][uu] + sp*accLds[2 + nt][gb][ul];
      float nv = accLds[6 + 4 + nt][gb][ul] + bias_lds[2][uu];
      float hn = sp*accLds[4 + nt][gb][ul];
      float r  = sigmoid_f(rv);
      float z  = sigmoid_f(zv);
      float n  = tanh_f(nv + r*(hn + bn_lds[uu]));
      float hp = sp * hp0;
      hnew0 = n + z*(hp - n);
      hp0 = hnew0;
      // publish ASAP: flight starts before the rest of phase C
      st_agent_u16(hs + ((size_t)t*4 + g)*8192 + sidx*512 + gb*32 + uu, f2bf_bits(hnew0));
    }
    {
      const float sp = rsqrtf(s1 + 1e-12f);
      float rv = accLds[6 + 0 + nt][gb+8][ul] + bias_lds[0][uu] + sp*accLds[0 + nt][gb+8][ul];
      float zv = accLds[6 + 2 + nt][gb+8][ul] + bias_lds[1][uu] + sp*accLds[2 + nt][gb+8][ul];
      float nv = accLds[6 + 4 + nt][gb+8][ul] + bias_lds[2][uu];
      float hn = sp*accLds[4 + nt][gb+8][ul];
      float r  = sigmoid_f(rv);
      float z  = sigmoid_f(zv);
      float n  = tanh_f(nv + r*(hn + bn_lds[uu]));
      float hp = sp * hp1;
      hnew1 = n + z*(hp - n);
      hp1 = hnew1;
      st_agent_u16(hs + ((size_t)t*4 + g)*8192 + sidx*512 + (gb+8)*32 + uu, f2bf_bits(hnew1));
    }
    // own chunk into LDS for next step
    tileOwn[gb*32 + uu]     = f2bf_bits(hnew0);
    tileOwn[(gb+8)*32 + uu] = f2bf_bits(hnew1);
    // prefetch first-pass loads of tile t (validated at phase A of t+1):
    // issued last so producers (incl. ourselves) had maximal time in flight.
    if (wave < 3 && t < NSTEP){
      const unsigned short* hb2 = hs + ((size_t)t*4 + g)*8192 + lm*32 + quad*8;
      #pragma unroll
      for (int k = 0; k < 16; k++)
        if (k != sidx) ch[k].v = *(const short8x*)(hb2 + (size_t)k*512);
    }
    barrier_lds();   // lgkm drain only: global stores/prefetch stay in flight
  }

  // epilogue: sumsq for t = NSTEP (one wave per group polls the final tile)
  if (sidx == 0 && wave == 0){
    unsigned long long* base =
      (unsigned long long*)(hs + ((size_t)NSTEP*4 + g)*8192 + lm*32 + quad*8);
    unsigned long long v0[16], v1[16];
    unsigned pend2 = 0xFFFFu;
    do {
      #pragma unroll
      for (int k = 0; k < 16; k++){
        if (pend2 & (1u<<k)){
          v0[k] = ld_agent_u64(base + (size_t)k*128);
          v1[k] = ld_agent_u64(base + (size_t)k*128 + 1);
        }
      }
      unsigned np = 0u;
      #pragma unroll
      for (int k = 0; k < 16; k++){
        if ((pend2 & (1u<<k)) && (has_ffff(v0[k]) | has_ffff(v1[k]))) np |= (1u<<k);
      }
      pend2 = np;
    } while (__any((int)pend2));
    float s = 0.f;
    #pragma unroll
    for (int k = 0; k < 16; k++) s += sq4(v0[k]) + sq4(v1[k]);
    s += __shfl_xor(s, 16, 64);
    s += __shfl_xor(s, 32, 64);
    if (lane < 16) sumsq[(size_t)NSTEP*64 + b0 + lane] = s;
  }
}

// ---------------------------------------------------------------------------
// Output GEMM with fused retract. hs layout [t][g][slice][bb][u].
// ---------------------------------------------------------------------------
__global__ __launch_bounds__(256, 2)
void k_ygemm(const unsigned short* __restrict__ hs, const float* __restrict__ sumsq,
             const unsigned short* __restrict__ wob, const float* __restrict__ b_out,
             float* __restrict__ out)
{
  const int t = blockIdx.x;
  const int tid = threadIdx.x, wave = tid >> 6, lane = tid & 63;
  const int lm = lane & 15, quad = lane >> 4;
  __shared__ float srow[64];
  __shared__ float bo[256];
  __shared__ float part[4][64];
  __shared__ float ysc[64];

  if (tid < 64) srow[tid] = rsqrtf(sumsq[(size_t)t*64 + tid] + 1e-12f);
  bo[tid] = b_out[tid];
  __syncthreads();

  f32x4 acc[4][4];
  #pragma unroll
  for (int mt = 0; mt < 4; mt++)
    #pragma unroll
    for (int nt = 0; nt < 4; nt++) acc[mt][nt] = (f32x4){0.f,0.f,0.f,0.f};

  const unsigned short* arow[4];
  const unsigned short* brow[4];
  #pragma unroll
  for (int mt = 0; mt < 4; mt++)
    arow[mt] = hs + ((size_t)t*4 + mt)*8192 + lm*32 + quad*8;
  #pragma unroll
  for (int nt = 0; nt < 4; nt++)
    brow[nt] = wob + ((size_t)(wave*64 + nt*16 + lm))*512 + quad*8;

  #pragma unroll 2
  for (int k = 0; k < 16; k++){
    short8x a[4], b[4];
    #pragma unroll
    for (int mt = 0; mt < 4; mt++) a[mt] = *(const short8x*)(arow[mt] + (size_t)k*512);
    #pragma unroll
    for (int nt = 0; nt < 4; nt++) b[nt] = *(const short8x*)(brow[nt] + k*32);
    #pragma unroll
    for (int mt = 0; mt < 4; mt++)
      #pragma unroll
      for (int nt = 0; nt < 4; nt++) acc[mt][nt] = MFMA(a[mt], b[nt], acc[mt][nt]);
  }

  float loc[4][4];
  #pragma unroll
  for (int mt = 0; mt < 4; mt++)
    #pragma unroll
    for (int r = 0; r < 4; r++) loc[mt][r] = 0.f;
  #pragma unroll
  for (int mt = 0; mt < 4; mt++){
    #pragma unroll
    for (int nt = 0; nt < 4; nt++){
      f32x4 v = acc[mt][nt];
      #pragma unroll
      for (int r = 0; r < 4; r++){
        int row = mt*16 + quad*4 + r;
        float y = srow[row]*v[r] + bo[wave*64 + nt*16 + lm];
        v[r] = y;
        loc[mt][r] += y*y;
      }
      acc[mt][nt] = v;
    }
  }
  #pragma unroll
  for (int off = 8; off; off >>= 1){
    #pragma unroll
    for (int mt = 0; mt < 4; mt++)
      #pragma unroll
      for (int r = 0; r < 4; r++) loc[mt][r] += __shfl_xor(loc[mt][r], off, 16);
  }
  if (lm == 0){
    #pragma unroll
    for (int mt = 0; mt < 4; mt++)
      #pragma unroll
      for (int r = 0; r < 4; r++) part[wave][mt*16 + quad*4 + r] = loc[mt][r];
  }
  __syncthreads();
  if (tid < 64) ysc[tid] = rsqrtf(part[0][tid] + part[1][tid] + part[2][tid] + part[3][tid] + 1e-12f);
  __syncthreads();

  #pragma unroll
  for (int mt = 0; mt < 4; mt++){
    #pragma unroll
    for (int nt = 0; nt < 4; nt++){
      #pragma unroll
      for (int r = 0; r < 4; r++){
        int row = mt*16 + quad*4 + r;
        int o   = wave*64 + nt*16 + lm;
        out[((size_t)row * T_ + t) * O_ + o] = acc[mt][nt][r] * ysc[row];
      }
    }
  }
}

// ---------------------------------------------------------------------------
extern "C" void kernel_launch(void* const* d_in, const int* in_sizes, int n_in,
                              void* d_out, int out_size, void* d_ws, size_t ws_size,
                              hipStream_t stream)
{
  (void)in_sizes; (void)n_in; (void)out_size;
  const float* cv   = (const float*)d_in[0];
  const float* w0   = (const float*)d_in[1];
  const float* b0v  = (const float*)d_in[2];
  const float* w1   = (const float*)d_in[3];
  const float* b1v  = (const float*)d_in[4];
  const float* w2   = (const float*)d_in[5];
  const float* b2v  = (const float*)d_in[6];
  const float* wih  = (const float*)d_in[7];
  const float* whh  = (const float*)d_in[8];
  const float* bg   = (const float*)d_in[9];
  const float* bn   = (const float*)d_in[10];
  const float* wout = (const float*)d_in[11];
  const float* bout = (const float*)d_in[12];
  float* out = (float*)d_out;

  // workspace layout
  const size_t HS_BYTES  = (size_t)T_ * B_ * H_ * 2;        // bf16 pre-retract h
  const size_t SS_BYTES  = (size_t)T_ * B_ * 4;
  const size_t OFF_SS    = HS_BYTES;
  const size_t OFF_WOB   = OFF_SS + SS_BYTES;
  const size_t NEED      = OFF_WOB + (size_t)O_ * H_ * 2;
  if (ws_size < NEED) return;

  unsigned short* hs    = (unsigned short*)d_ws;
  float*          sumsq = (float*)((char*)d_ws + OFF_SS);
  unsigned short* wob   = (unsigned short*)((char*)d_ws + OFF_WOB);

  // sentinel prefill of hs[t>=1]: 0xFFFF bf16 (-NaN), unreachable from finite math
  const size_t T0_BYTES = (size_t)4 * 8192 * 2;
  hipMemsetAsync((char*)d_ws + T0_BYTES, 0xFF, HS_BYTES - T0_BYTES, stream);

  hipLaunchKernelGGL(k_mlp,   dim3(64),   dim3(256), 0, stream,
                     cv, w0, b0v, w1, b1v, w2, b2v, hs);
  hipLaunchKernelGGL(k_wcvt,  dim3(512),  dim3(256), 0, stream, wout, wob);
  hipLaunchKernelGGL(k_scan,  dim3(64),   dim3(256), 0, stream,
                     cv, wih, whh, bg, bn, hs, sumsq);
  hipLaunchKernelGGL(k_ygemm, dim3(2048), dim3(256), 0, stream,
                     hs, sumsq, wob, bout, out);
}

// Round 5
// 9637.171 us; speedup vs baseline: 1.9672x; 1.9672x over previous
//
#include <hip/hip_runtime.h>
#include <math.h>

#define B_  64
#define T_  2048
#define C_  256
#define H_  512
#define O_  256
#define NSTEP 2047

typedef __attribute__((ext_vector_type(8))) short short8x;
typedef __attribute__((ext_vector_type(4))) float f32x4;

__device__ __forceinline__ unsigned short f2bf_bits(float x){
  unsigned int u = __builtin_bit_cast(unsigned int, x);
  u = u + 0x7FFFu + ((u >> 16) & 1u);      // RNE
  return (unsigned short)(u >> 16);
}
__device__ __forceinline__ float bf2f(unsigned short h){
  unsigned int u = ((unsigned int)h) << 16;
  return __builtin_bit_cast(float, u);
}
__device__ __forceinline__ short8x pack8(float4 a, float4 b){
  short8x w;
  w[0]=(short)f2bf_bits(a.x); w[1]=(short)f2bf_bits(a.y);
  w[2]=(short)f2bf_bits(a.z); w[3]=(short)f2bf_bits(a.w);
  w[4]=(short)f2bf_bits(b.x); w[5]=(short)f2bf_bits(b.y);
  w[6]=(short)f2bf_bits(b.z); w[7]=(short)f2bf_bits(b.w);
  return w;
}
__device__ __forceinline__ f32x4 MFMA(short8x a, short8x b, f32x4 c){
  return __builtin_amdgcn_mfma_f32_16x16x32_bf16(a, b, c, 0, 0, 0);
}
__device__ __forceinline__ float softplus_f(float x){
  return (x > 20.f) ? x : log1pf(expf(x));
}
__device__ __forceinline__ float fast_exp2(float x){ return __builtin_amdgcn_exp2f(x); }
__device__ __forceinline__ float fast_rcp(float x){ return __builtin_amdgcn_rcpf(x); }
__device__ __forceinline__ float sigmoid_f(float x){
  return fast_rcp(1.f + fast_exp2(-1.44269504f * x));
}
__device__ __forceinline__ float tanh_f(float x){
  return 1.f - 2.f * fast_rcp(1.f + fast_exp2(2.88539008f * x));
}

// agent-scope ops: bypass stale L1/L2, hit the device coherence point (LLC).
__device__ __forceinline__ void st_agent_u16(unsigned short* p, unsigned short v){
  __hip_atomic_store(p, v, __ATOMIC_RELAXED, __HIP_MEMORY_SCOPE_AGENT);
}
__device__ __forceinline__ unsigned long long ld_agent_u64(unsigned long long* p){
  return __hip_atomic_load(p, __ATOMIC_RELAXED, __HIP_MEMORY_SCOPE_AGENT);
}

// any 16-bit field == 0xFFFF (sentinel = -NaN bf16, unreachable from finite math)
__device__ __forceinline__ int has_ffff(unsigned long long w){
  unsigned long long nv = ~w;
  return ((nv - 0x0001000100010001ull) & ~nv & 0x8000800080008000ull) != 0ull;
}
__device__ __forceinline__ float sq4(unsigned long long w){
  unsigned lo = (unsigned)w, hi = (unsigned)(w >> 32);
  float f0 = __builtin_bit_cast(float, lo << 16);
  float f1 = __builtin_bit_cast(float, lo & 0xFFFF0000u);
  float f2 = __builtin_bit_cast(float, hi << 16);
  float f3 = __builtin_bit_cast(float, hi & 0xFFFF0000u);
  return f0*f0 + f1*f1 + f2*f2 + f3*f3;
}

union ChunkU { short8x v; unsigned long long q[2]; };

// barrier with LDS-drain only (no vmcnt(0): do NOT serialize on store-ack)
__device__ __forceinline__ void barrier_lds(){
  asm volatile("s_waitcnt lgkmcnt(0)" ::: "memory");
  __builtin_amdgcn_s_barrier();
  asm volatile("" ::: "memory");
}

// hs layout: [t][g(4)][slice(16)][bb(16)][u(32)] bf16
// index(t,g,s,bb,u) = ((t*4+g)*8192) + s*512 + bb*32 + u   (in shorts)

// ---------------------------------------------------------------------------
// Init MLP -> hs[t=0] (pre-retract bf16).
// ---------------------------------------------------------------------------
__global__ void k_mlp(const float* __restrict__ cv,
                      const float* __restrict__ w0, const float* __restrict__ bb0,
                      const float* __restrict__ w1, const float* __restrict__ bb1,
                      const float* __restrict__ w2, const float* __restrict__ bb2,
                      unsigned short* __restrict__ hs)
{
  const int b = blockIdx.x, tid = threadIdx.x;
  const int wave = tid >> 6, lane = tid & 63;
  __shared__ float xr[256], a0[512], a1[512], a2[512];

  xr[tid] = cv[(size_t)b * T_ * C_ + tid];
  __syncthreads();

  for (int i = 0; i < 32; i++){
    float s[4];
    #pragma unroll
    for (int uu = 0; uu < 4; uu++){
      int j = wave*128 + i*4 + uu;
      const float4* wr = (const float4*)(w0 + (size_t)j * 256);
      float4 w = wr[lane];
      s[uu] = w.x*xr[lane*4+0] + w.y*xr[lane*4+1] + w.z*xr[lane*4+2] + w.w*xr[lane*4+3];
    }
    #pragma unroll
    for (int off = 32; off; off >>= 1){
      #pragma unroll
      for (int uu = 0; uu < 4; uu++) s[uu] += __shfl_xor(s[uu], off, 64);
    }
    if (lane < 4){ int j = wave*128 + i*4 + lane; a0[j] = softplus_f(s[lane] + bb0[j]); }
  }
  __syncthreads();

  for (int i = 0; i < 32; i++){
    float s[4];
    #pragma unroll
    for (int uu = 0; uu < 4; uu++){
      int j = wave*128 + i*4 + uu;
      const float4* wr = (const float4*)(w1 + (size_t)j * 512);
      float4 wA = wr[lane*2], wB = wr[lane*2+1];
      int k0 = lane*8;
      s[uu] = wA.x*a0[k0]   + wA.y*a0[k0+1] + wA.z*a0[k0+2] + wA.w*a0[k0+3]
            + wB.x*a0[k0+4] + wB.y*a0[k0+5] + wB.z*a0[k0+6] + wB.w*a0[k0+7];
    }
    #pragma unroll
    for (int off = 32; off; off >>= 1){
      #pragma unroll
      for (int uu = 0; uu < 4; uu++) s[uu] += __shfl_xor(s[uu], off, 64);
    }
    if (lane < 4){ int j = wave*128 + i*4 + lane; a1[j] = softplus_f(s[lane] + bb1[j]); }
  }
  __syncthreads();

  for (int i = 0; i < 32; i++){
    float s[4];
    #pragma unroll
    for (int uu = 0; uu < 4; uu++){
      int j = wave*128 + i*4 + uu;
      const float4* wr = (const float4*)(w2 + (size_t)j * 512);
      float4 wA = wr[lane*2], wB = wr[lane*2+1];
      int k0 = lane*8;
      s[uu] = wA.x*a1[k0]   + wA.y*a1[k0+1] + wA.z*a1[k0+2] + wA.w*a1[k0+3]
            + wB.x*a1[k0+4] + wB.y*a1[k0+5] + wB.z*a1[k0+6] + wB.w*a1[k0+7];
    }
    #pragma unroll
    for (int off = 32; off; off >>= 1){
      #pragma unroll
      for (int uu = 0; uu < 4; uu++) s[uu] += __shfl_xor(s[uu], off, 64);
    }
    if (lane < 4){ int j = wave*128 + i*4 + lane; a2[j] = s[lane] + bb2[j]; }
  }
  __syncthreads();

  const int g = b >> 4, bb = b & 15;
  {
    int u = tid;
    hs[(size_t)g*8192 + (u>>5)*512 + bb*32 + (u&31)] = f2bf_bits(a2[u]);
    u = tid + 256;
    hs[(size_t)g*8192 + (u>>5)*512 + bb*32 + (u&31)] = f2bf_bits(a2[u]);
  }
}

// ---------------------------------------------------------------------------
__global__ void k_wcvt(const float* __restrict__ w, unsigned short* __restrict__ o)
{
  int idx = blockIdx.x * 256 + threadIdx.x;
  if (idx < O_ * H_) o[idx] = f2bf_bits(w[idx]);
}

// ---------------------------------------------------------------------------
// Persistent GRU scan, v5 = r3 protocol verbatim + ONE change:
// wave 3's cv row for step t+1 is loaded during step t (cross-step register
// prefetch), so the cold-HBM cv latency no longer sits on the critical path.
// h-tile loads stay at phase A (r3's proven-safe placement; r4's early tile
// prefetch read pre-publication sentinels and collapsed into retry storms).
// 64 wgs = 4 batch-groups x 16 unit-slices.
// ---------------------------------------------------------------------------
__global__ __launch_bounds__(256, 1)
void k_scan(const float* __restrict__ cv, const float* __restrict__ w_ih,
            const float* __restrict__ w_hh, const float* __restrict__ bias,
            const float* __restrict__ b_n,
            unsigned short* __restrict__ hs, float* __restrict__ sumsq)
{
  const int wg   = blockIdx.x;
  const int g    = wg >> 4;         // batch group 0..3
  const int sidx = wg & 15;         // unit slice 0..15
  const int b0   = g * 16;
  const int u0   = sidx * 32;
  const int tid  = threadIdx.x;
  const int wave = tid >> 6, lane = tid & 63;
  const int lm   = lane & 15, quad = lane >> 4;
  const int gb   = tid >> 5;        // 0..7
  const int uu   = tid & 31;

  __shared__ float accLds[12][16][16];       // 0..5 hh (gate*2+nt), 6..11 ih
  __shared__ float ssqR[3][16];              // per-wave sumsq partials per batch
  __shared__ unsigned short tileOwn[512];    // own slice's h_{t-1} chunk (1 KiB)
  __shared__ float bias_lds[3][32];
  __shared__ float bn_lds[32];

  if (tid < 32){
    bias_lds[0][tid] = bias[u0 + tid];
    bias_lds[1][tid] = bias[512 + u0 + tid];
    bias_lds[2][tid] = bias[1024 + u0 + tid];
    bn_lds[tid]      = b_n[u0 + tid];
  }
  // own pre-retract h (fp32) in registers
  float hp0 = bf2f(hs[(size_t)g*8192 + sidx*512 + gb*32 + uu]);
  float hp1 = bf2f(hs[(size_t)g*8192 + sidx*512 + (gb+8)*32 + uu]);
  // stage own chunk of h_0 in LDS (consumed at t=1 phase A)
  tileOwn[gb*32 + uu]     = f2bf_bits(hp0);
  tileOwn[(gb+8)*32 + uu] = f2bf_bits(hp1);

  // ---- weight fragments in registers (bf16), loaded once ----
  short8x wreg[48];
  if (wave < 3){
    const int gate = wave;
    #pragma unroll
    for (int nt = 0; nt < 2; nt++){
      #pragma unroll
      for (int k = 0; k < 16; k++){
        const float* p = w_hh + ((size_t)(gate*512 + u0 + nt*16 + lm)) * 512 + k*32 + quad*8;
        wreg[nt*16 + k] = pack8(*(const float4*)p, *(const float4*)(p + 4));
      }
    }
  } else {
    #pragma unroll
    for (int g2 = 0; g2 < 3; g2++){
      #pragma unroll
      for (int nt = 0; nt < 2; nt++){
        #pragma unroll
        for (int kk = 0; kk < 8; kk++){
          const float* p = w_ih + ((size_t)(g2*512 + u0 + nt*16 + lm)) * 256 + kk*32 + quad*8;
          wreg[(g2*2 + nt)*8 + kk] = pack8(*(const float4*)p, *(const float4*)(p + 4));
        }
      }
    }
  }

  // ---- cross-step cv prefetch state (wave 3): row for step t+1 in flight ----
  float4 cvp[16];
  if (wave == 3){
    const size_t xbase = ((size_t)(b0 + lm) * T_ + 1) * C_;
    #pragma unroll
    for (int kk = 0; kk < 8; kk++){
      const float* xp = cv + xbase + kk*32 + quad*8;
      cvp[2*kk]   = *(const float4*)xp;
      cvp[2*kk+1] = *(const float4*)(xp + 4);
    }
  }
  __syncthreads();

  for (int t = 1; t <= NSTEP; t++){
    if (wave < 3){
      // ---- phase A: cached tile load + sentinel validation ----
      short8x ownv = *(const short8x*)&tileOwn[lm*32 + quad*8];
      const unsigned short* hb = hs + ((size_t)(t-1)*4 + g)*8192 + lm*32 + quad*8;
      ChunkU ch[16];
      #pragma unroll
      for (int k = 0; k < 16; k++){
        if (k == sidx) ch[k].v = ownv;
        else           ch[k].v = *(const short8x*)(hb + (size_t)k*512);
      }
      unsigned pend = 0xFFFFu & ~(1u << sidx);
      int spin = 0;
      for (;;){
        unsigned np = 0u;
        #pragma unroll
        for (int k = 0; k < 16; k++)
          if (((pend >> k) & 1u) && (has_ffff(ch[k].q[0]) | has_ffff(ch[k].q[1])))
            np |= 1u << k;
        if (!__any((int)np)) break;
        pend = np;
        if (spin++) __builtin_amdgcn_s_sleep(1);   // backoff: don't hammer the fabric
        #pragma unroll
        for (int k = 0; k < 16; k++)
          if ((pend >> k) & 1u){
            unsigned long long* p = (unsigned long long*)(hb + (size_t)k*512);
            ch[k].q[0] = ld_agent_u64(p);
            ch[k].q[1] = ld_agent_u64(p + 1);
          }
      }

      // ---- hh-GEMM from registers ----
      f32x4 acc0 = {0.f,0.f,0.f,0.f}, acc1 = {0.f,0.f,0.f,0.f};
      #pragma unroll
      for (int k = 0; k < 16; k++){
        acc0 = MFMA(ch[k].v, wreg[k],      acc0);
        acc1 = MFMA(ch[k].v, wreg[16 + k], acc1);
      }
      #pragma unroll
      for (int r = 0; r < 4; r++){
        accLds[wave*2 + 0][quad*4 + r][lm] = acc0[r];
        accLds[wave*2 + 1][quad*4 + r][lm] = acc1[r];
      }

      // ---- in-wave sumsq of h_{t-1} (k-ranges 6/5/5 across waves 0..2) ----
      const int klo = (wave == 0) ? 0 : (wave == 1 ? 6 : 11);
      const int khi = (wave == 0) ? 6 : (wave == 1 ? 11 : 16);
      float s = 0.f;
      #pragma unroll
      for (int k = 0; k < 16; k++){
        if (k >= klo && k < khi) s += sq4(ch[k].q[0]) + sq4(ch[k].q[1]);
      }
      s += __shfl_xor(s, 16, 64);   // reduce over the 4 quads of batch lm
      s += __shfl_xor(s, 32, 64);
      if (lane < 16) ssqR[wave][lane] = s;
    } else {
      // ---- ih GEMM from prefetched cv registers ----
      short8x af[8];
      #pragma unroll
      for (int kk = 0; kk < 8; kk++) af[kk] = pack8(cvp[2*kk], cvp[2*kk+1]);
      // issue cv loads for t+1 immediately: a full step of latency hiding
      if (t < NSTEP){
        const size_t xbase = ((size_t)(b0 + lm) * T_ + (t+1)) * C_;
        #pragma unroll
        for (int kk = 0; kk < 8; kk++){
          const float* xp = cv + xbase + kk*32 + quad*8;
          cvp[2*kk]   = *(const float4*)xp;
          cvp[2*kk+1] = *(const float4*)(xp + 4);
        }
      }
      f32x4 acc[6];
      #pragma unroll
      for (int tt = 0; tt < 6; tt++) acc[tt] = (f32x4){0.f,0.f,0.f,0.f};
      #pragma unroll
      for (int kk = 0; kk < 8; kk++){
        #pragma unroll
        for (int tt = 0; tt < 6; tt++) acc[tt] = MFMA(af[kk], wreg[tt*8 + kk], acc[tt]);
      }
      #pragma unroll
      for (int tt = 0; tt < 6; tt++){
        #pragma unroll
        for (int r = 0; r < 4; r++) accLds[6 + tt][quad*4 + r][lm] = acc[tt][r];
      }
    }
    barrier_lds();

    // ---------------- gate phase (all 256 threads, 2 elems each) ----------------
    const float s0 = ssqR[0][gb]   + ssqR[1][gb]   + ssqR[2][gb];
    const float s1 = ssqR[0][gb+8] + ssqR[1][gb+8] + ssqR[2][gb+8];
    if (sidx == 0 && uu == 0){
      sumsq[(size_t)(t-1)*64 + b0 + gb]     = s0;
      sumsq[(size_t)(t-1)*64 + b0 + gb + 8] = s1;
    }
    const int nt = uu >> 4, ul = uu & 15;
    float hnew0, hnew1;
    {
      const float sp = rsqrtf(s0 + 1e-12f);
      float rv = accLds[6 + 0 + nt][gb][ul] + bias_lds[0][uu] + sp*accLds[0 + nt][gb][ul];
      float zv = accLds[6 + 2 + nt][gb][ul] + bias_lds[1][uu] + sp*accLds[2 + nt][gb][ul];
      float nv = accLds[6 + 4 + nt][gb][ul] + bias_lds[2][uu];
      float hn = sp*accLds[4 + nt][gb][ul];
      float r  = sigmoid_f(rv);
      float z  = sigmoid_f(zv);
      float n  = tanh_f(nv + r*(hn + bn_lds[uu]));
      float hp = sp * hp0;
      hnew0 = n + z*(hp - n);
      hp0 = hnew0;
    }
    {
      const float sp = rsqrtf(s1 + 1e-12f);
      float rv = accLds[6 + 0 + nt][gb+8][ul] + bias_lds[0][uu] + sp*accLds[0 + nt][gb+8][ul];
      float zv = accLds[6 + 2 + nt][gb+8][ul] + bias_lds[1][uu] + sp*accLds[2 + nt][gb+8][ul];
      float nv = accLds[6 + 4 + nt][gb+8][ul] + bias_lds[2][uu];
      float hn = sp*accLds[4 + nt][gb+8][ul];
      float r  = sigmoid_f(rv);
      float z  = sigmoid_f(zv);
      float n  = tanh_f(nv + r*(hn + bn_lds[uu]));
      float hp = sp * hp1;
      hnew1 = n + z*(hp - n);
      hp1 = hnew1;
    }
    const unsigned short hb0 = f2bf_bits(hnew0), hb1 = f2bf_bits(hnew1);
    // own chunk into LDS for next step (removes dependence on own global stores)
    tileOwn[gb*32 + uu]     = hb0;
    tileOwn[(gb+8)*32 + uu] = hb1;
    // publish to global (agent scope; consumers validate, so no drain needed)
    st_agent_u16(hs + ((size_t)t*4 + g)*8192 + sidx*512 + gb*32 + uu,     hb0);
    st_agent_u16(hs + ((size_t)t*4 + g)*8192 + sidx*512 + (gb+8)*32 + uu, hb1);
    barrier_lds();   // lgkm drain only: global stores stay in flight
  }

  // epilogue: sumsq for t = NSTEP (one wave per group polls the final tile)
  if (sidx == 0 && wave == 0){
    unsigned long long* base =
      (unsigned long long*)(hs + ((size_t)NSTEP*4 + g)*8192 + lm*32 + quad*8);
    unsigned long long v0[16], v1[16];
    unsigned pend2 = 0xFFFFu;
    do {
      #pragma unroll
      for (int k = 0; k < 16; k++){
        if (pend2 & (1u<<k)){
          v0[k] = ld_agent_u64(base + (size_t)k*128);
          v1[k] = ld_agent_u64(base + (size_t)k*128 + 1);
        }
      }
      unsigned np = 0u;
      #pragma unroll
      for (int k = 0; k < 16; k++){
        if ((pend2 & (1u<<k)) && (has_ffff(v0[k]) | has_ffff(v1[k]))) np |= (1u<<k);
      }
      pend2 = np;
    } while (__any((int)pend2));
    float s = 0.f;
    #pragma unroll
    for (int k = 0; k < 16; k++) s += sq4(v0[k]) + sq4(v1[k]);
    s += __shfl_xor(s, 16, 64);
    s += __shfl_xor(s, 32, 64);
    if (lane < 16) sumsq[(size_t)NSTEP*64 + b0 + lane] = s;
  }
}

// ---------------------------------------------------------------------------
// Output GEMM with fused retract. hs layout [t][g][slice][bb][u].
// ---------------------------------------------------------------------------
__global__ __launch_bounds__(256, 2)
void k_ygemm(const unsigned short* __restrict__ hs, const float* __restrict__ sumsq,
             const unsigned short* __restrict__ wob, const float* __restrict__ b_out,
             float* __restrict__ out)
{
  const int t = blockIdx.x;
  const int tid = threadIdx.x, wave = tid >> 6, lane = tid & 63;
  const int lm = lane & 15, quad = lane >> 4;
  __shared__ float srow[64];
  __shared__ float bo[256];
  __shared__ float part[4][64];
  __shared__ float ysc[64];

  if (tid < 64) srow[tid] = rsqrtf(sumsq[(size_t)t*64 + tid] + 1e-12f);
  bo[tid] = b_out[tid];
  __syncthreads();

  f32x4 acc[4][4];
  #pragma unroll
  for (int mt = 0; mt < 4; mt++)
    #pragma unroll
    for (int nt = 0; nt < 4; nt++) acc[mt][nt] = (f32x4){0.f,0.f,0.f,0.f};

  const unsigned short* arow[4];
  const unsigned short* brow[4];
  #pragma unroll
  for (int mt = 0; mt < 4; mt++)
    arow[mt] = hs + ((size_t)t*4 + mt)*8192 + lm*32 + quad*8;
  #pragma unroll
  for (int nt = 0; nt < 4; nt++)
    brow[nt] = wob + ((size_t)(wave*64 + nt*16 + lm))*512 + quad*8;

  #pragma unroll 2
  for (int k = 0; k < 16; k++){
    short8x a[4], b[4];
    #pragma unroll
    for (int mt = 0; mt < 4; mt++) a[mt] = *(const short8x*)(arow[mt] + (size_t)k*512);
    #pragma unroll
    for (int nt = 0; nt < 4; nt++) b[nt] = *(const short8x*)(brow[nt] + k*32);
    #pragma unroll
    for (int mt = 0; mt < 4; mt++)
      #pragma unroll
      for (int nt = 0; nt < 4; nt++) acc[mt][nt] = MFMA(a[mt], b[nt], acc[mt][nt]);
  }

  float loc[4][4];
  #pragma unroll
  for (int mt = 0; mt < 4; mt++)
    #pragma unroll
    for (int r = 0; r < 4; r++) loc[mt][r] = 0.f;
  #pragma unroll
  for (int mt = 0; mt < 4; mt++){
    #pragma unroll
    for (int nt = 0; nt < 4; nt++){
      f32x4 v = acc[mt][nt];
      #pragma unroll
      for (int r = 0; r < 4; r++){
        int row = mt*16 + quad*4 + r;
        float y = srow[row]*v[r] + bo[wave*64 + nt*16 + lm];
        v[r] = y;
        loc[mt][r] += y*y;
      }
      acc[mt][nt] = v;
    }
  }
  #pragma unroll
  for (int off = 8; off; off >>= 1){
    #pragma unroll
    for (int mt = 0; mt < 4; mt++)
      #pragma unroll
      for (int r = 0; r < 4; r++) loc[mt][r] += __shfl_xor(loc[mt][r], off, 16);
  }
  if (lm == 0){
    #pragma unroll
    for (int mt = 0; mt < 4; mt++)
      #pragma unroll
      for (int r = 0; r < 4; r++) part[wave][mt*16 + quad*4 + r] = loc[mt][r];
  }
  __syncthreads();
  if (tid < 64) ysc[tid] = rsqrtf(part[0][tid] + part[1][tid] + part[2][tid] + part[3][tid] + 1e-12f);
  __syncthreads();

  #pragma unroll
  for (int mt = 0; mt < 4; mt++){
    #pragma unroll
    for (int nt = 0; nt < 4; nt++){
      #pragma unroll
      for (int r = 0; r < 4; r++){
        int row = mt*16 + quad*4 + r;
        int o   = wave*64 + nt*16 + lm;
        out[((size_t)row * T_ + t) * O_ + o] = acc[mt][nt][r] * ysc[row];
      }
    }
  }
}

// ---------------------------------------------------------------------------
extern "C" void kernel_launch(void* const* d_in, const int* in_sizes, int n_in,
                              void* d_out, int out_size, void* d_ws, size_t ws_size,
                              hipStream_t stream)
{
  (void)in_sizes; (void)n_in; (void)out_size;
  const float* cv   = (const float*)d_in[0];
  const float* w0   = (const float*)d_in[1];
  const float* b0v  = (const float*)d_in[2];
  const float* w1   = (const float*)d_in[3];
  const float* b1v  = (const float*)d_in[4];
  const float* w2   = (const float*)d_in[5];
  const float* b2v  = (const float*)d_in[6];
  const float* wih  = (const float*)d_in[7];
  const float* whh  = (const float*)d_in[8];
  const float* bg   = (const float*)d_in[9];
  const float* bn   = (const float*)d_in[10];
  const float* wout = (const float*)d_in[11];
  const float* bout = (const float*)d_in[12];
  float* out = (float*)d_out;

  // workspace layout
  const size_t HS_BYTES  = (size_t)T_ * B_ * H_ * 2;        // bf16 pre-retract h
  const size_t SS_BYTES  = (size_t)T_ * B_ * 4;
  const size_t OFF_SS    = HS_BYTES;
  const size_t OFF_WOB   = OFF_SS + SS_BYTES;
  const size_t NEED      = OFF_WOB + (size_t)O_ * H_ * 2;
  if (ws_size < NEED) return;

  unsigned short* hs    = (unsigned short*)d_ws;
  float*          sumsq = (float*)((char*)d_ws + OFF_SS);
  unsigned short* wob   = (unsigned short*)((char*)d_ws + OFF_WOB);

  // sentinel prefill of hs[t>=1]: 0xFFFF bf16 (-NaN), unreachable from finite math
  const size_t T0_BYTES = (size_t)4 * 8192 * 2;
  hipMemsetAsync((char*)d_ws + T0_BYTES, 0xFF, HS_BYTES - T0_BYTES, stream);

  hipLaunchKernelGGL(k_mlp,   dim3(64),   dim3(256), 0, stream,
                     cv, w0, b0v, w1, b1v, w2, b2v, hs);
  hipLaunchKernelGGL(k_wcvt,  dim3(512),  dim3(256), 0, stream, wout, wob);
  hipLaunchKernelGGL(k_scan,  dim3(64),   dim3(256), 0, stream,
                     cv, wih, whh, bg, bn, hs, sumsq);
  hipLaunchKernelGGL(k_ygemm, dim3(2048), dim3(256), 0, stream,
                     hs, sumsq, wob, bout, out);
}

// Round 6
// 8855.769 us; speedup vs baseline: 2.1408x; 1.0882x over previous
//
#include <hip/hip_runtime.h>
#include <math.h>

#define B_  64
#define T_  2048
#define C_  256
#define H_  512
#define O_  256
#define NSTEP 2047

typedef __attribute__((ext_vector_type(8))) short short8x;
typedef __attribute__((ext_vector_type(4))) float f32x4;

__device__ __forceinline__ unsigned short f2bf_bits(float x){
  unsigned int u = __builtin_bit_cast(unsigned int, x);
  u = u + 0x7FFFu + ((u >> 16) & 1u);      // RNE
  return (unsigned short)(u >> 16);
}
__device__ __forceinline__ float bf2f(unsigned short h){
  unsigned int u = ((unsigned int)h) << 16;
  return __builtin_bit_cast(float, u);
}
__device__ __forceinline__ short8x pack8(float4 a, float4 b){
  short8x w;
  w[0]=(short)f2bf_bits(a.x); w[1]=(short)f2bf_bits(a.y);
  w[2]=(short)f2bf_bits(a.z); w[3]=(short)f2bf_bits(a.w);
  w[4]=(short)f2bf_bits(b.x); w[5]=(short)f2bf_bits(b.y);
  w[6]=(short)f2bf_bits(b.z); w[7]=(short)f2bf_bits(b.w);
  return w;
}
__device__ __forceinline__ f32x4 MFMA(short8x a, short8x b, f32x4 c){
  return __builtin_amdgcn_mfma_f32_16x16x32_bf16(a, b, c, 0, 0, 0);
}
__device__ __forceinline__ float softplus_f(float x){
  return (x > 20.f) ? x : log1pf(expf(x));
}
__device__ __forceinline__ float fast_exp2(float x){ return __builtin_amdgcn_exp2f(x); }
__device__ __forceinline__ float fast_rcp(float x){ return __builtin_amdgcn_rcpf(x); }
__device__ __forceinline__ float sigmoid_f(float x){
  return fast_rcp(1.f + fast_exp2(-1.44269504f * x));
}
__device__ __forceinline__ float tanh_f(float x){
  return 1.f - 2.f * fast_rcp(1.f + fast_exp2(2.88539008f * x));
}

// agent-scope ops: bypass stale L1/L2, hit the device coherence point (LLC).
__device__ __forceinline__ void st_agent_u16(unsigned short* p, unsigned short v){
  __hip_atomic_store(p, v, __ATOMIC_RELAXED, __HIP_MEMORY_SCOPE_AGENT);
}
__device__ __forceinline__ unsigned long long ld_agent_u64(unsigned long long* p){
  return __hip_atomic_load(p, __ATOMIC_RELAXED, __HIP_MEMORY_SCOPE_AGENT);
}

// any 16-bit field == 0xFFFF (sentinel = -NaN bf16, unreachable from finite math)
__device__ __forceinline__ int has_ffff(unsigned long long w){
  unsigned long long nv = ~w;
  return ((nv - 0x0001000100010001ull) & ~nv & 0x8000800080008000ull) != 0ull;
}
__device__ __forceinline__ float sq4(unsigned long long w){
  unsigned lo = (unsigned)w, hi = (unsigned)(w >> 32);
  float f0 = __builtin_bit_cast(float, lo << 16);
  float f1 = __builtin_bit_cast(float, lo & 0xFFFF0000u);
  float f2 = __builtin_bit_cast(float, hi << 16);
  float f3 = __builtin_bit_cast(float, hi & 0xFFFF0000u);
  return f0*f0 + f1*f1 + f2*f2 + f3*f3;
}

union ChunkU { short8x v; unsigned long long q[2]; };

// barrier with LDS-drain only (no vmcnt(0): do NOT serialize on store-ack)
__device__ __forceinline__ void barrier_lds(){
  asm volatile("s_waitcnt lgkmcnt(0)" ::: "memory");
  __builtin_amdgcn_s_barrier();
  asm volatile("" ::: "memory");
}

// hs layout: [t][g(4)][slice(16)][bb(16)][u(32)] bf16
// index(t,g,s,bb,u) = ((t*4+g)*8192) + s*512 + bb*32 + u   (in shorts)

// ---------------------------------------------------------------------------
// Init MLP -> hs[t=0] (pre-retract bf16).
// ---------------------------------------------------------------------------
__global__ void k_mlp(const float* __restrict__ cv,
                      const float* __restrict__ w0, const float* __restrict__ bb0,
                      const float* __restrict__ w1, const float* __restrict__ bb1,
                      const float* __restrict__ w2, const float* __restrict__ bb2,
                      unsigned short* __restrict__ hs)
{
  const int b = blockIdx.x, tid = threadIdx.x;
  const int wave = tid >> 6, lane = tid & 63;
  __shared__ float xr[256], a0[512], a1[512], a2[512];

  xr[tid] = cv[(size_t)b * T_ * C_ + tid];
  __syncthreads();

  for (int i = 0; i < 32; i++){
    float s[4];
    #pragma unroll
    for (int uu = 0; uu < 4; uu++){
      int j = wave*128 + i*4 + uu;
      const float4* wr = (const float4*)(w0 + (size_t)j * 256);
      float4 w = wr[lane];
      s[uu] = w.x*xr[lane*4+0] + w.y*xr[lane*4+1] + w.z*xr[lane*4+2] + w.w*xr[lane*4+3];
    }
    #pragma unroll
    for (int off = 32; off; off >>= 1){
      #pragma unroll
      for (int uu = 0; uu < 4; uu++) s[uu] += __shfl_xor(s[uu], off, 64);
    }
    if (lane < 4){ int j = wave*128 + i*4 + lane; a0[j] = softplus_f(s[lane] + bb0[j]); }
  }
  __syncthreads();

  for (int i = 0; i < 32; i++){
    float s[4];
    #pragma unroll
    for (int uu = 0; uu < 4; uu++){
      int j = wave*128 + i*4 + uu;
      const float4* wr = (const float4*)(w1 + (size_t)j * 512);
      float4 wA = wr[lane*2], wB = wr[lane*2+1];
      int k0 = lane*8;
      s[uu] = wA.x*a0[k0]   + wA.y*a0[k0+1] + wA.z*a0[k0+2] + wA.w*a0[k0+3]
            + wB.x*a0[k0+4] + wB.y*a0[k0+5] + wB.z*a0[k0+6] + wB.w*a0[k0+7];
    }
    #pragma unroll
    for (int off = 32; off; off >>= 1){
      #pragma unroll
      for (int uu = 0; uu < 4; uu++) s[uu] += __shfl_xor(s[uu], off, 64);
    }
    if (lane < 4){ int j = wave*128 + i*4 + lane; a1[j] = softplus_f(s[lane] + bb1[j]); }
  }
  __syncthreads();

  for (int i = 0; i < 32; i++){
    float s[4];
    #pragma unroll
    for (int uu = 0; uu < 4; uu++){
      int j = wave*128 + i*4 + uu;
      const float4* wr = (const float4*)(w2 + (size_t)j * 512);
      float4 wA = wr[lane*2], wB = wr[lane*2+1];
      int k0 = lane*8;
      s[uu] = wA.x*a1[k0]   + wA.y*a1[k0+1] + wA.z*a1[k0+2] + wA.w*a1[k0+3]
            + wB.x*a1[k0+4] + wB.y*a1[k0+5] + wB.z*a1[k0+6] + wB.w*a1[k0+7];
    }
    #pragma unroll
    for (int off = 32; off; off >>= 1){
      #pragma unroll
      for (int uu = 0; uu < 4; uu++) s[uu] += __shfl_xor(s[uu], off, 64);
    }
    if (lane < 4){ int j = wave*128 + i*4 + lane; a2[j] = s[lane] + bb2[j]; }
  }
  __syncthreads();

  const int g = b >> 4, bb = b & 15;
  {
    int u = tid;
    hs[(size_t)g*8192 + (u>>5)*512 + bb*32 + (u&31)] = f2bf_bits(a2[u]);
    u = tid + 256;
    hs[(size_t)g*8192 + (u>>5)*512 + bb*32 + (u&31)] = f2bf_bits(a2[u]);
  }
}

// ---------------------------------------------------------------------------
__global__ void k_wcvt(const float* __restrict__ w, unsigned short* __restrict__ o)
{
  int idx = blockIdx.x * 256 + threadIdx.x;
  if (idx < O_ * H_) o[idx] = f2bf_bits(w[idx]);
}

// ---------------------------------------------------------------------------
// Persistent GRU scan, v6 = r3 data path + MFMA-while-retry interleave:
// per pass, straggler retries are ISSUED first and already-valid chunks are
// MFMA'd while those loads are in flight (retry RTT overlaps compute).
// h-halves publish immediately when computed. No traffic-pattern changes.
// 64 wgs = 4 batch-groups x 16 unit-slices.
// ---------------------------------------------------------------------------
__global__ __launch_bounds__(256, 1)
void k_scan(const float* __restrict__ cv, const float* __restrict__ w_ih,
            const float* __restrict__ w_hh, const float* __restrict__ bias,
            const float* __restrict__ b_n,
            unsigned short* __restrict__ hs, float* __restrict__ sumsq)
{
  const int wg   = blockIdx.x;
  const int g    = wg >> 4;         // batch group 0..3
  const int sidx = wg & 15;         // unit slice 0..15
  const int b0   = g * 16;
  const int u0   = sidx * 32;
  const int tid  = threadIdx.x;
  const int wave = tid >> 6, lane = tid & 63;
  const int lm   = lane & 15, quad = lane >> 4;
  const int gb   = tid >> 5;        // 0..7
  const int uu   = tid & 31;

  __shared__ float accLds[12][16][16];       // 0..5 hh (gate*2+nt), 6..11 ih
  __shared__ float ssqR[3][16];              // per-wave sumsq partials per batch
  __shared__ unsigned short tileOwn[512];    // own slice's h_{t-1} chunk (1 KiB)
  __shared__ float bias_lds[3][32];
  __shared__ float bn_lds[32];

  if (tid < 32){
    bias_lds[0][tid] = bias[u0 + tid];
    bias_lds[1][tid] = bias[512 + u0 + tid];
    bias_lds[2][tid] = bias[1024 + u0 + tid];
    bn_lds[tid]      = b_n[u0 + tid];
  }
  // own pre-retract h (fp32) in registers
  float hp0 = bf2f(hs[(size_t)g*8192 + sidx*512 + gb*32 + uu]);
  float hp1 = bf2f(hs[(size_t)g*8192 + sidx*512 + (gb+8)*32 + uu]);
  // stage own chunk of h_0 in LDS (consumed at t=1 phase A)
  tileOwn[gb*32 + uu]     = f2bf_bits(hp0);
  tileOwn[(gb+8)*32 + uu] = f2bf_bits(hp1);

  // ---- weight fragments in registers (bf16), loaded once ----
  short8x wreg[48];
  if (wave < 3){
    const int gate = wave;
    #pragma unroll
    for (int nt = 0; nt < 2; nt++){
      #pragma unroll
      for (int k = 0; k < 16; k++){
        const float* p = w_hh + ((size_t)(gate*512 + u0 + nt*16 + lm)) * 512 + k*32 + quad*8;
        wreg[nt*16 + k] = pack8(*(const float4*)p, *(const float4*)(p + 4));
      }
    }
  } else {
    #pragma unroll
    for (int g2 = 0; g2 < 3; g2++){
      #pragma unroll
      for (int nt = 0; nt < 2; nt++){
        #pragma unroll
        for (int kk = 0; kk < 8; kk++){
          const float* p = w_ih + ((size_t)(g2*512 + u0 + nt*16 + lm)) * 256 + kk*32 + quad*8;
          wreg[(g2*2 + nt)*8 + kk] = pack8(*(const float4*)p, *(const float4*)(p + 4));
        }
      }
    }
  }
  __syncthreads();

  for (int t = 1; t <= NSTEP; t++){
    if (wave < 3){
      // ---- phase A: cached first-pass tile load ----
      short8x ownv = *(const short8x*)&tileOwn[lm*32 + quad*8];
      const unsigned short* hb = hs + ((size_t)(t-1)*4 + g)*8192 + lm*32 + quad*8;
      ChunkU ch[16];
      #pragma unroll
      for (int k = 0; k < 16; k++){
        if (k == sidx) ch[k].v = ownv;
        else           ch[k].v = *(const short8x*)(hb + (size_t)k*512);
      }

      // ---- validate / retry / MFMA interleave ----
      const int klo = (wave == 0) ? 0 : (wave == 1 ? 6 : 11);
      const int khi = (wave == 0) ? 6 : (wave == 1 ? 11 : 16);
      f32x4 acc0 = {0.f,0.f,0.f,0.f}, acc1 = {0.f,0.f,0.f,0.f};
      float s = 0.f;
      unsigned done = 0u;
      int spin = 0;
      while (done != 0xFFFFu){
        // per-lane validity of not-yet-consumed chunks
        unsigned lanebad = 0u;
        #pragma unroll
        for (int k = 0; k < 16; k++)
          if (!((done >> k) & 1u) && (has_ffff(ch[k].q[0]) | has_ffff(ch[k].q[1])))
            lanebad |= 1u << k;
        // wave-uniform bad set (OR-reduce across 64 lanes)
        #pragma unroll
        for (int off = 32; off; off >>= 1) lanebad |= __shfl_xor(lanebad, off, 64);
        const unsigned newgood = 0xFFFFu & ~lanebad & ~done;
        const unsigned pendm   = 0xFFFFu & ~done & lanebad;
        // issue straggler retries FIRST (flight overlaps the MFMA below)
        if (pendm){
          if (!newgood && spin++) __builtin_amdgcn_s_sleep(1);  // pure-spin backoff
          #pragma unroll
          for (int k = 0; k < 16; k++)
            if ((pendm >> k) & 1u){
              unsigned long long* p = (unsigned long long*)(hb + (size_t)k*512);
              ch[k].q[0] = ld_agent_u64(p);
              ch[k].q[1] = ld_agent_u64(p + 1);
            }
        }
        // MFMA + sumsq over newly valid chunks while retries are in flight
        #pragma unroll
        for (int k = 0; k < 16; k++)
          if ((newgood >> k) & 1u){
            acc0 = MFMA(ch[k].v, wreg[k],      acc0);
            acc1 = MFMA(ch[k].v, wreg[16 + k], acc1);
            if (k >= klo && k < khi) s += sq4(ch[k].q[0]) + sq4(ch[k].q[1]);
          }
        done |= newgood;
      }

      #pragma unroll
      for (int r = 0; r < 4; r++){
        accLds[wave*2 + 0][quad*4 + r][lm] = acc0[r];
        accLds[wave*2 + 1][quad*4 + r][lm] = acc1[r];
      }
      s += __shfl_xor(s, 16, 64);   // reduce over the 4 quads of batch lm
      s += __shfl_xor(s, 32, 64);
      if (lane < 16) ssqR[wave][lane] = s;
    } else {
      // ---- ih GEMM (r3 placement: load + consume in phase A) ----
      short8x af[8];
      const size_t xbase = ((size_t)(b0 + lm) * T_ + t) * C_;
      #pragma unroll
      for (int kk = 0; kk < 8; kk++){
        const float* xp = cv + xbase + kk*32 + quad*8;
        af[kk] = pack8(*(const float4*)xp, *(const float4*)(xp + 4));
      }
      f32x4 acc[6];
      #pragma unroll
      for (int tt = 0; tt < 6; tt++) acc[tt] = (f32x4){0.f,0.f,0.f,0.f};
      #pragma unroll
      for (int kk = 0; kk < 8; kk++){
        #pragma unroll
        for (int tt = 0; tt < 6; tt++) acc[tt] = MFMA(af[kk], wreg[tt*8 + kk], acc[tt]);
      }
      #pragma unroll
      for (int tt = 0; tt < 6; tt++){
        #pragma unroll
        for (int r = 0; r < 4; r++) accLds[6 + tt][quad*4 + r][lm] = acc[tt][r];
      }
    }
    barrier_lds();

    // ---------------- gate phase (all 256 threads, 2 elems each) ----------------
    const float s0 = ssqR[0][gb]   + ssqR[1][gb]   + ssqR[2][gb];
    const float s1 = ssqR[0][gb+8] + ssqR[1][gb+8] + ssqR[2][gb+8];
    const int nt = uu >> 4, ul = uu & 15;
    float hnew0, hnew1;
    {
      const float sp = rsqrtf(s0 + 1e-12f);
      float rv = accLds[6 + 0 + nt][gb][ul] + bias_lds[0][uu] + sp*accLds[0 + nt][gb][ul];
      float zv = accLds[6 + 2 + nt][gb][ul] + bias_lds[1][uu] + sp*accLds[2 + nt][gb][ul];
      float nv = accLds[6 + 4 + nt][gb][ul] + bias_lds[2][uu];
      float hn = sp*accLds[4 + nt][gb][ul];
      float r  = sigmoid_f(rv);
      float z  = sigmoid_f(zv);
      float n  = tanh_f(nv + r*(hn + bn_lds[uu]));
      float hp = sp * hp0;
      hnew0 = n + z*(hp - n);
      hp0 = hnew0;
      // publish ASAP: store flight starts before the second half's VALU
      st_agent_u16(hs + ((size_t)t*4 + g)*8192 + sidx*512 + gb*32 + uu, f2bf_bits(hnew0));
    }
    {
      const float sp = rsqrtf(s1 + 1e-12f);
      float rv = accLds[6 + 0 + nt][gb+8][ul] + bias_lds[0][uu] + sp*accLds[0 + nt][gb+8][ul];
      float zv = accLds[6 + 2 + nt][gb+8][ul] + bias_lds[1][uu] + sp*accLds[2 + nt][gb+8][ul];
      float nv = accLds[6 + 4 + nt][gb+8][ul] + bias_lds[2][uu];
      float hn = sp*accLds[4 + nt][gb+8][ul];
      float r  = sigmoid_f(rv);
      float z  = sigmoid_f(zv);
      float n  = tanh_f(nv + r*(hn + bn_lds[uu]));
      float hp = sp * hp1;
      hnew1 = n + z*(hp - n);
      hp1 = hnew1;
      st_agent_u16(hs + ((size_t)t*4 + g)*8192 + sidx*512 + (gb+8)*32 + uu, f2bf_bits(hnew1));
    }
    // own chunk into LDS for next step (no dependence on own global stores)
    tileOwn[gb*32 + uu]     = f2bf_bits(hnew0);
    tileOwn[(gb+8)*32 + uu] = f2bf_bits(hnew1);
    if (sidx == 0 && uu == 0){
      sumsq[(size_t)(t-1)*64 + b0 + gb]     = s0;
      sumsq[(size_t)(t-1)*64 + b0 + gb + 8] = s1;
    }
    barrier_lds();   // lgkm drain only: global stores stay in flight
  }

  // epilogue: sumsq for t = NSTEP (one wave per group polls the final tile)
  if (sidx == 0 && wave == 0){
    unsigned long long* base =
      (unsigned long long*)(hs + ((size_t)NSTEP*4 + g)*8192 + lm*32 + quad*8);
    unsigned long long v0[16], v1[16];
    unsigned pend2 = 0xFFFFu;
    do {
      #pragma unroll
      for (int k = 0; k < 16; k++){
        if (pend2 & (1u<<k)){
          v0[k] = ld_agent_u64(base + (size_t)k*128);
          v1[k] = ld_agent_u64(base + (size_t)k*128 + 1);
        }
      }
      unsigned np = 0u;
      #pragma unroll
      for (int k = 0; k < 16; k++){
        if ((pend2 & (1u<<k)) && (has_ffff(v0[k]) | has_ffff(v1[k]))) np |= (1u<<k);
      }
      pend2 = np;
    } while (__any((int)pend2));
    float s = 0.f;
    #pragma unroll
    for (int k = 0; k < 16; k++) s += sq4(v0[k]) + sq4(v1[k]);
    s += __shfl_xor(s, 16, 64);
    s += __shfl_xor(s, 32, 64);
    if (lane < 16) sumsq[(size_t)NSTEP*64 + b0 + lane] = s;
  }
}

// ---------------------------------------------------------------------------
// Output GEMM with fused retract. hs layout [t][g][slice][bb][u].
// ---------------------------------------------------------------------------
__global__ __launch_bounds__(256, 2)
void k_ygemm(const unsigned short* __restrict__ hs, const float* __restrict__ sumsq,
             const unsigned short* __restrict__ wob, const float* __restrict__ b_out,
             float* __restrict__ out)
{
  const int t = blockIdx.x;
  const int tid = threadIdx.x, wave = tid >> 6, lane = tid & 63;
  const int lm = lane & 15, quad = lane >> 4;
  __shared__ float srow[64];
  __shared__ float bo[256];
  __shared__ float part[4][64];
  __shared__ float ysc[64];

  if (tid < 64) srow[tid] = rsqrtf(sumsq[(size_t)t*64 + tid] + 1e-12f);
  bo[tid] = b_out[tid];
  __syncthreads();

  f32x4 acc[4][4];
  #pragma unroll
  for (int mt = 0; mt < 4; mt++)
    #pragma unroll
    for (int nt = 0; nt < 4; nt++) acc[mt][nt] = (f32x4){0.f,0.f,0.f,0.f};

  const unsigned short* arow[4];
  const unsigned short* brow[4];
  #pragma unroll
  for (int mt = 0; mt < 4; mt++)
    arow[mt] = hs + ((size_t)t*4 + mt)*8192 + lm*32 + quad*8;
  #pragma unroll
  for (int nt = 0; nt < 4; nt++)
    brow[nt] = wob + ((size_t)(wave*64 + nt*16 + lm))*512 + quad*8;

  #pragma unroll 2
  for (int k = 0; k < 16; k++){
    short8x a[4], b[4];
    #pragma unroll
    for (int mt = 0; mt < 4; mt++) a[mt] = *(const short8x*)(arow[mt] + (size_t)k*512);
    #pragma unroll
    for (int nt = 0; nt < 4; nt++) b[nt] = *(const short8x*)(brow[nt] + k*32);
    #pragma unroll
    for (int mt = 0; mt < 4; mt++)
      #pragma unroll
      for (int nt = 0; nt < 4; nt++) acc[mt][nt] = MFMA(a[mt], b[nt], acc[mt][nt]);
  }

  float loc[4][4];
  #pragma unroll
  for (int mt = 0; mt < 4; mt++)
    #pragma unroll
    for (int r = 0; r < 4; r++) loc[mt][r] = 0.f;
  #pragma unroll
  for (int mt = 0; mt < 4; mt++){
    #pragma unroll
    for (int nt = 0; nt < 4; nt++){
      f32x4 v = acc[mt][nt];
      #pragma unroll
      for (int r = 0; r < 4; r++){
        int row = mt*16 + quad*4 + r;
        float y = srow[row]*v[r] + bo[wave*64 + nt*16 + lm];
        v[r] = y;
        loc[mt][r] += y*y;
      }
      acc[mt][nt] = v;
    }
  }
  #pragma unroll
  for (int off = 8; off; off >>= 1){
    #pragma unroll
    for (int mt = 0; mt < 4; mt++)
      #pragma unroll
      for (int r = 0; r < 4; r++) loc[mt][r] += __shfl_xor(loc[mt][r], off, 16);
  }
  if (lm == 0){
    #pragma unroll
    for (int mt = 0; mt < 4; mt++)
      #pragma unroll
      for (int r = 0; r < 4; r++) part[wave][mt*16 + quad*4 + r] = loc[mt][r];
  }
  __syncthreads();
  if (tid < 64) ysc[tid] = rsqrtf(part[0][tid] + part[1][tid] + part[2][tid] + part[3][tid] + 1e-12f);
  __syncthreads();

  #pragma unroll
  for (int mt = 0; mt < 4; mt++){
    #pragma unroll
    for (int nt = 0; nt < 4; nt++){
      #pragma unroll
      for (int r = 0; r < 4; r++){
        int row = mt*16 + quad*4 + r;
        int o   = wave*64 + nt*16 + lm;
        out[((size_t)row * T_ + t) * O_ + o] = acc[mt][nt][r] * ysc[row];
      }
    }
  }
}

// ---------------------------------------------------------------------------
extern "C" void kernel_launch(void* const* d_in, const int* in_sizes, int n_in,
                              void* d_out, int out_size, void* d_ws, size_t ws_size,
                              hipStream_t stream)
{
  (void)in_sizes; (void)n_in; (void)out_size;
  const float* cv   = (const float*)d_in[0];
  const float* w0   = (const float*)d_in[1];
  const float* b0v  = (const float*)d_in[2];
  const float* w1   = (const float*)d_in[3];
  const float* b1v  = (const float*)d_in[4];
  const float* w2   = (const float*)d_in[5];
  const float* b2v  = (const float*)d_in[6];
  const float* wih  = (const float*)d_in[7];
  const float* whh  = (const float*)d_in[8];
  const float* bg   = (const float*)d_in[9];
  const float* bn   = (const float*)d_in[10];
  const float* wout = (const float*)d_in[11];
  const float* bout = (const float*)d_in[12];
  float* out = (float*)d_out;

  // workspace layout
  const size_t HS_BYTES  = (size_t)T_ * B_ * H_ * 2;        // bf16 pre-retract h
  const size_t SS_BYTES  = (size_t)T_ * B_ * 4;
  const size_t OFF_SS    = HS_BYTES;
  const size_t OFF_WOB   = OFF_SS + SS_BYTES;
  const size_t NEED      = OFF_WOB + (size_t)O_ * H_ * 2;
  if (ws_size < NEED) return;

  unsigned short* hs    = (unsigned short*)d_ws;
  float*          sumsq = (float*)((char*)d_ws + OFF_SS);
  unsigned short* wob   = (unsigned short*)((char*)d_ws + OFF_WOB);

  // sentinel prefill of hs[t>=1]: 0xFFFF bf16 (-NaN), unreachable from finite math
  const size_t T0_BYTES = (size_t)4 * 8192 * 2;
  hipMemsetAsync((char*)d_ws + T0_BYTES, 0xFF, HS_BYTES - T0_BYTES, stream);

  hipLaunchKernelGGL(k_mlp,   dim3(64),   dim3(256), 0, stream,
                     cv, w0, b0v, w1, b1v, w2, b2v, hs);
  hipLaunchKernelGGL(k_wcvt,  dim3(512),  dim3(256), 0, stream, wout, wob);
  hipLaunchKernelGGL(k_scan,  dim3(64),   dim3(256), 0, stream,
                     cv, wih, whh, bg, bn, hs, sumsq);
  hipLaunchKernelGGL(k_ygemm, dim3(2048), dim3(256), 0, stream,
                     hs, sumsq, wob, bout, out);
}

// Round 8
// 7807.161 us; speedup vs baseline: 2.4283x; 1.1343x over previous
//
#include <hip/hip_runtime.h>
#include <math.h>

#define B_  64
#define T_  2048
#define C_  256
#define H_  512
#define O_  256
#define NSTEP 2047

typedef __attribute__((ext_vector_type(8))) short short8x;
typedef __attribute__((ext_vector_type(4))) float f32x4;

__device__ __forceinline__ unsigned short f2bf_bits(float x){
  unsigned int u = __builtin_bit_cast(unsigned int, x);
  u = u + 0x7FFFu + ((u >> 16) & 1u);      // RNE
  return (unsigned short)(u >> 16);
}
__device__ __forceinline__ float bf2f(unsigned short h){
  unsigned int u = ((unsigned int)h) << 16;
  return __builtin_bit_cast(float, u);
}
__device__ __forceinline__ short8x pack8(float4 a, float4 b){
  short8x w;
  w[0]=(short)f2bf_bits(a.x); w[1]=(short)f2bf_bits(a.y);
  w[2]=(short)f2bf_bits(a.z); w[3]=(short)f2bf_bits(a.w);
  w[4]=(short)f2bf_bits(b.x); w[5]=(short)f2bf_bits(b.y);
  w[6]=(short)f2bf_bits(b.z); w[7]=(short)f2bf_bits(b.w);
  return w;
}
__device__ __forceinline__ f32x4 MFMA(short8x a, short8x b, f32x4 c){
  return __builtin_amdgcn_mfma_f32_16x16x32_bf16(a, b, c, 0, 0, 0);
}
__device__ __forceinline__ float softplus_f(float x){
  return (x > 20.f) ? x : log1pf(expf(x));
}
__device__ __forceinline__ float fast_exp2(float x){ return __builtin_amdgcn_exp2f(x); }
__device__ __forceinline__ float fast_rcp(float x){ return __builtin_amdgcn_rcpf(x); }
__device__ __forceinline__ float sigmoid_f(float x){
  return fast_rcp(1.f + fast_exp2(-1.44269504f * x));
}
__device__ __forceinline__ float tanh_f(float x){
  return 1.f - 2.f * fast_rcp(1.f + fast_exp2(2.88539008f * x));
}

// agent-scope ops: bypass stale L1/L2, hit the device coherence point (LLC).
__device__ __forceinline__ void st_agent_u16(unsigned short* p, unsigned short v){
  __hip_atomic_store(p, v, __ATOMIC_RELAXED, __HIP_MEMORY_SCOPE_AGENT);
}
__device__ __forceinline__ unsigned long long ld_agent_u64(unsigned long long* p){
  return __hip_atomic_load(p, __ATOMIC_RELAXED, __HIP_MEMORY_SCOPE_AGENT);
}

// any 16-bit field == 0xFFFF (sentinel = -NaN bf16, unreachable from finite math)
__device__ __forceinline__ int has_ffff(unsigned long long w){
  unsigned long long nv = ~w;
  return ((nv - 0x0001000100010001ull) & ~nv & 0x8000800080008000ull) != 0ull;
}
__device__ __forceinline__ float sq4(unsigned long long w){
  unsigned lo = (unsigned)w, hi = (unsigned)(w >> 32);
  float f0 = __builtin_bit_cast(float, lo << 16);
  float f1 = __builtin_bit_cast(float, lo & 0xFFFF0000u);
  float f2 = __builtin_bit_cast(float, hi << 16);
  float f3 = __builtin_bit_cast(float, hi & 0xFFFF0000u);
  return f0*f0 + f1*f1 + f2*f2 + f3*f3;
}

union ChunkU { short8x v; unsigned long long q[2]; };

// barrier with LDS-drain only (no vmcnt(0): do NOT serialize on store-ack)
__device__ __forceinline__ void barrier_lds(){
  asm volatile("s_waitcnt lgkmcnt(0)" ::: "memory");
  __builtin_amdgcn_s_barrier();
  asm volatile("" ::: "memory");
}

// hs layout: [t][g(4)][slice(16)][bb(16)][u(32)] bf16
// index(t,g,s,bb,u) = ((t*4+g)*8192) + s*512 + bb*32 + u   (in shorts)

// ---------------------------------------------------------------------------
// Init MLP -> hs[t=0] (pre-retract bf16).
// ---------------------------------------------------------------------------
__global__ void k_mlp(const float* __restrict__ cv,
                      const float* __restrict__ w0, const float* __restrict__ bb0,
                      const float* __restrict__ w1, const float* __restrict__ bb1,
                      const float* __restrict__ w2, const float* __restrict__ bb2,
                      unsigned short* __restrict__ hs)
{
  const int b = blockIdx.x, tid = threadIdx.x;
  const int wave = tid >> 6, lane = tid & 63;
  __shared__ float xr[256], a0[512], a1[512], a2[512];

  xr[tid] = cv[(size_t)b * T_ * C_ + tid];
  __syncthreads();

  for (int i = 0; i < 32; i++){
    float s[4];
    #pragma unroll
    for (int uu = 0; uu < 4; uu++){
      int j = wave*128 + i*4 + uu;
      const float4* wr = (const float4*)(w0 + (size_t)j * 256);
      float4 w = wr[lane];
      s[uu] = w.x*xr[lane*4+0] + w.y*xr[lane*4+1] + w.z*xr[lane*4+2] + w.w*xr[lane*4+3];
    }
    #pragma unroll
    for (int off = 32; off; off >>= 1){
      #pragma unroll
      for (int uu = 0; uu < 4; uu++) s[uu] += __shfl_xor(s[uu], off, 64);
    }
    if (lane < 4){ int j = wave*128 + i*4 + lane; a0[j] = softplus_f(s[lane] + bb0[j]); }
  }
  __syncthreads();

  for (int i = 0; i < 32; i++){
    float s[4];
    #pragma unroll
    for (int uu = 0; uu < 4; uu++){
      int j = wave*128 + i*4 + uu;
      const float4* wr = (const float4*)(w1 + (size_t)j * 512);
      float4 wA = wr[lane*2], wB = wr[lane*2+1];
      int k0 = lane*8;
      s[uu] = wA.x*a0[k0]   + wA.y*a0[k0+1] + wA.z*a0[k0+2] + wA.w*a0[k0+3]
            + wB.x*a0[k0+4] + wB.y*a0[k0+5] + wB.z*a0[k0+6] + wB.w*a0[k0+7];
    }
    #pragma unroll
    for (int off = 32; off; off >>= 1){
      #pragma unroll
      for (int uu = 0; uu < 4; uu++) s[uu] += __shfl_xor(s[uu], off, 64);
    }
    if (lane < 4){ int j = wave*128 + i*4 + lane; a1[j] = softplus_f(s[lane] + bb1[j]); }
  }
  __syncthreads();

  for (int i = 0; i < 32; i++){
    float s[4];
    #pragma unroll
    for (int uu = 0; uu < 4; uu++){
      int j = wave*128 + i*4 + uu;
      const float4* wr = (const float4*)(w2 + (size_t)j * 512);
      float4 wA = wr[lane*2], wB = wr[lane*2+1];
      int k0 = lane*8;
      s[uu] = wA.x*a1[k0]   + wA.y*a1[k0+1] + wA.z*a1[k0+2] + wA.w*a1[k0+3]
            + wB.x*a1[k0+4] + wB.y*a1[k0+5] + wB.z*a1[k0+6] + wB.w*a1[k0+7];
    }
    #pragma unroll
    for (int off = 32; off; off >>= 1){
      #pragma unroll
      for (int uu = 0; uu < 4; uu++) s[uu] += __shfl_xor(s[uu], off, 64);
    }
    if (lane < 4){ int j = wave*128 + i*4 + lane; a2[j] = s[lane] + bb2[j]; }
  }
  __syncthreads();

  const int g = b >> 4, bb = b & 15;
  {
    int u = tid;
    hs[(size_t)g*8192 + (u>>5)*512 + bb*32 + (u&31)] = f2bf_bits(a2[u]);
    u = tid + 256;
    hs[(size_t)g*8192 + (u>>5)*512 + bb*32 + (u&31)] = f2bf_bits(a2[u]);
  }
}

// ---------------------------------------------------------------------------
__global__ void k_wcvt(const float* __restrict__ w, unsigned short* __restrict__ o)
{
  int idx = blockIdx.x * 256 + threadIdx.x;
  if (idx < O_ * H_) o[idx] = f2bf_bits(w[idx]);
}

// ---------------------------------------------------------------------------
// Persistent GRU scan (best verified variant, r3): cached first-pass tile
// loads + sentinel validation (no flags, no vmcnt drain) + agent-scope
// per-chunk retry with backoff. Own chunk via LDS so the loop-end barrier
// never waits on the wg's own global stores.
// 64 wgs = 4 batch-groups x 16 unit-slices.
// ---------------------------------------------------------------------------
__global__ __launch_bounds__(256, 1)
void k_scan(const float* __restrict__ cv, const float* __restrict__ w_ih,
            const float* __restrict__ w_hh, const float* __restrict__ bias,
            const float* __restrict__ b_n,
            unsigned short* __restrict__ hs, float* __restrict__ sumsq)
{
  const int wg   = blockIdx.x;
  const int g    = wg >> 4;         // batch group 0..3
  const int sidx = wg & 15;         // unit slice 0..15
  const int b0   = g * 16;
  const int u0   = sidx * 32;
  const int tid  = threadIdx.x;
  const int wave = tid >> 6, lane = tid & 63;
  const int lm   = lane & 15, quad = lane >> 4;
  const int gb   = tid >> 5;        // 0..7
  const int uu   = tid & 31;

  __shared__ float accLds[12][16][16];       // 0..5 hh (gate*2+nt), 6..11 ih
  __shared__ float ssqR[3][16];              // per-wave sumsq partials per batch
  __shared__ unsigned short tileOwn[512];    // own slice's h_{t-1} chunk (1 KiB)
  __shared__ float bias_lds[3][32];
  __shared__ float bn_lds[32];

  if (tid < 32){
    bias_lds[0][tid] = bias[u0 + tid];
    bias_lds[1][tid] = bias[512 + u0 + tid];
    bias_lds[2][tid] = bias[1024 + u0 + tid];
    bn_lds[tid]      = b_n[u0 + tid];
  }
  // own pre-retract h (fp32) in registers
  float hp0 = bf2f(hs[(size_t)g*8192 + sidx*512 + gb*32 + uu]);
  float hp1 = bf2f(hs[(size_t)g*8192 + sidx*512 + (gb+8)*32 + uu]);
  // stage own chunk of h_0 in LDS (consumed at t=1 phase A)
  tileOwn[gb*32 + uu]     = f2bf_bits(hp0);
  tileOwn[(gb+8)*32 + uu] = f2bf_bits(hp1);

  // ---- weight fragments in registers (bf16), loaded once ----
  short8x wreg[48];
  if (wave < 3){
    const int gate = wave;
    #pragma unroll
    for (int nt = 0; nt < 2; nt++){
      #pragma unroll
      for (int k = 0; k < 16; k++){
        const float* p = w_hh + ((size_t)(gate*512 + u0 + nt*16 + lm)) * 512 + k*32 + quad*8;
        wreg[nt*16 + k] = pack8(*(const float4*)p, *(const float4*)(p + 4));
      }
    }
  } else {
    #pragma unroll
    for (int g2 = 0; g2 < 3; g2++){
      #pragma unroll
      for (int nt = 0; nt < 2; nt++){
        #pragma unroll
        for (int kk = 0; kk < 8; kk++){
          const float* p = w_ih + ((size_t)(g2*512 + u0 + nt*16 + lm)) * 256 + kk*32 + quad*8;
          wreg[(g2*2 + nt)*8 + kk] = pack8(*(const float4*)p, *(const float4*)(p + 4));
        }
      }
    }
  }
  __syncthreads();

  for (int t = 1; t <= NSTEP; t++){
    if (wave < 3){
      // ---- phase A: cached tile load + sentinel validation ----
      short8x ownv = *(const short8x*)&tileOwn[lm*32 + quad*8];
      const unsigned short* hb = hs + ((size_t)(t-1)*4 + g)*8192 + lm*32 + quad*8;
      ChunkU ch[16];
      #pragma unroll
      for (int k = 0; k < 16; k++){
        if (k == sidx) ch[k].v = ownv;
        else           ch[k].v = *(const short8x*)(hb + (size_t)k*512);
      }
      unsigned pend = 0xFFFFu & ~(1u << sidx);
      int spin = 0;
      for (;;){
        unsigned np = 0u;
        #pragma unroll
        for (int k = 0; k < 16; k++)
          if (((pend >> k) & 1u) && (has_ffff(ch[k].q[0]) | has_ffff(ch[k].q[1])))
            np |= 1u << k;
        if (!__any((int)np)) break;
        pend = np;
        if (spin++) __builtin_amdgcn_s_sleep(1);   // backoff: don't hammer the fabric
        #pragma unroll
        for (int k = 0; k < 16; k++)
          if ((pend >> k) & 1u){
            unsigned long long* p = (unsigned long long*)(hb + (size_t)k*512);
            ch[k].q[0] = ld_agent_u64(p);
            ch[k].q[1] = ld_agent_u64(p + 1);
          }
      }

      // ---- hh-GEMM from registers ----
      f32x4 acc0 = {0.f,0.f,0.f,0.f}, acc1 = {0.f,0.f,0.f,0.f};
      #pragma unroll
      for (int k = 0; k < 16; k++){
        acc0 = MFMA(ch[k].v, wreg[k],      acc0);
        acc1 = MFMA(ch[k].v, wreg[16 + k], acc1);
      }
      #pragma unroll
      for (int r = 0; r < 4; r++){
        accLds[wave*2 + 0][quad*4 + r][lm] = acc0[r];
        accLds[wave*2 + 1][quad*4 + r][lm] = acc1[r];
      }

      // ---- in-wave sumsq of h_{t-1} (k-ranges 6/5/5 across waves 0..2) ----
      const int klo = (wave == 0) ? 0 : (wave == 1 ? 6 : 11);
      const int khi = (wave == 0) ? 6 : (wave == 1 ? 11 : 16);
      float s = 0.f;
      #pragma unroll
      for (int k = 0; k < 16; k++){
        if (k >= klo && k < khi) s += sq4(ch[k].q[0]) + sq4(ch[k].q[1]);
      }
      s += __shfl_xor(s, 16, 64);   // reduce over the 4 quads of batch lm
      s += __shfl_xor(s, 32, 64);
      if (lane < 16) ssqR[wave][lane] = s;
    } else {
      // ---- ih GEMM (no cross-wg dependency) ----
      short8x af[8];
      const size_t xbase = ((size_t)(b0 + lm) * T_ + t) * C_;
      #pragma unroll
      for (int kk = 0; kk < 8; kk++){
        const float* xp = cv + xbase + kk*32 + quad*8;
        af[kk] = pack8(*(const float4*)xp, *(const float4*)(xp + 4));
      }
      f32x4 acc[6];
      #pragma unroll
      for (int tt = 0; tt < 6; tt++) acc[tt] = (f32x4){0.f,0.f,0.f,0.f};
      #pragma unroll
      for (int kk = 0; kk < 8; kk++){
        #pragma unroll
        for (int tt = 0; tt < 6; tt++) acc[tt] = MFMA(af[kk], wreg[tt*8 + kk], acc[tt]);
      }
      #pragma unroll
      for (int tt = 0; tt < 6; tt++){
        #pragma unroll
        for (int r = 0; r < 4; r++) accLds[6 + tt][quad*4 + r][lm] = acc[tt][r];
      }
    }
    barrier_lds();

    // ---------------- gate phase (all 256 threads, 2 elems each) ----------------
    const float s0 = ssqR[0][gb]   + ssqR[1][gb]   + ssqR[2][gb];
    const float s1 = ssqR[0][gb+8] + ssqR[1][gb+8] + ssqR[2][gb+8];
    if (sidx == 0 && uu == 0){
      sumsq[(size_t)(t-1)*64 + b0 + gb]     = s0;
      sumsq[(size_t)(t-1)*64 + b0 + gb + 8] = s1;
    }
    const int nt = uu >> 4, ul = uu & 15;
    float hnew0, hnew1;
    {
      const float sp = rsqrtf(s0 + 1e-12f);
      float rv = accLds[6 + 0 + nt][gb][ul] + bias_lds[0][uu] + sp*accLds[0 + nt][gb][ul];
      float zv = accLds[6 + 2 + nt][gb][ul] + bias_lds[1][uu] + sp*accLds[2 + nt][gb][ul];
      float nv = accLds[6 + 4 + nt][gb][ul] + bias_lds[2][uu];
      float hn = sp*accLds[4 + nt][gb][ul];
      float r  = sigmoid_f(rv);
      float z  = sigmoid_f(zv);
      float n  = tanh_f(nv + r*(hn + bn_lds[uu]));
      float hp = sp * hp0;
      hnew0 = n + z*(hp - n);
      hp0 = hnew0;
    }
    {
      const float sp = rsqrtf(s1 + 1e-12f);
      float rv = accLds[6 + 0 + nt][gb+8][ul] + bias_lds[0][uu] + sp*accLds[0 + nt][gb+8][ul];
      float zv = accLds[6 + 2 + nt][gb+8][ul] + bias_lds[1][uu] + sp*accLds[2 + nt][gb+8][ul];
      float nv = accLds[6 + 4 + nt][gb+8][ul] + bias_lds[2][uu];
      float hn = sp*accLds[4 + nt][gb+8][ul];
      float r  = sigmoid_f(rv);
      float z  = sigmoid_f(zv);
      float n  = tanh_f(nv + r*(hn + bn_lds[uu]));
      float hp = sp * hp1;
      hnew1 = n + z*(hp - n);
      hp1 = hnew1;
    }
    const unsigned short hb0 = f2bf_bits(hnew0), hb1 = f2bf_bits(hnew1);
    // own chunk into LDS for next step (removes dependence on own global stores)
    tileOwn[gb*32 + uu]     = hb0;
    tileOwn[(gb+8)*32 + uu] = hb1;
    // publish to global (agent scope; consumers validate, so no drain needed)
    st_agent_u16(hs + ((size_t)t*4 + g)*8192 + sidx*512 + gb*32 + uu,     hb0);
    st_agent_u16(hs + ((size_t)t*4 + g)*8192 + sidx*512 + (gb+8)*32 + uu, hb1);
    barrier_lds();   // lgkm drain only: global stores stay in flight
  }

  // epilogue: sumsq for t = NSTEP (one wave per group polls the final tile)
  if (sidx == 0 && wave == 0){
    unsigned long long* base =
      (unsigned long long*)(hs + ((size_t)NSTEP*4 + g)*8192 + lm*32 + quad*8);
    unsigned long long v0[16], v1[16];
    unsigned pend2 = 0xFFFFu;
    do {
      #pragma unroll
      for (int k = 0; k < 16; k++){
        if (pend2 & (1u<<k)){
          v0[k] = ld_agent_u64(base + (size_t)k*128);
          v1[k] = ld_agent_u64(base + (size_t)k*128 + 1);
        }
      }
      unsigned np = 0u;
      #pragma unroll
      for (int k = 0; k < 16; k++){
        if ((pend2 & (1u<<k)) && (has_ffff(v0[k]) | has_ffff(v1[k]))) np |= (1u<<k);
      }
      pend2 = np;
    } while (__any((int)pend2));
    float s = 0.f;
    #pragma unroll
    for (int k = 0; k < 16; k++) s += sq4(v0[k]) + sq4(v1[k]);
    s += __shfl_xor(s, 16, 64);
    s += __shfl_xor(s, 32, 64);
    if (lane < 16) sumsq[(size_t)NSTEP*64 + b0 + lane] = s;
  }
}

// ---------------------------------------------------------------------------
// Output GEMM with fused retract. hs layout [t][g][slice][bb][u].
// ---------------------------------------------------------------------------
__global__ __launch_bounds__(256, 2)
void k_ygemm(const unsigned short* __restrict__ hs, const float* __restrict__ sumsq,
             const unsigned short* __restrict__ wob, const float* __restrict__ b_out,
             float* __restrict__ out)
{
  const int t = blockIdx.x;
  const int tid = threadIdx.x, wave = tid >> 6, lane = tid & 63;
  const int lm = lane & 15, quad = lane >> 4;
  __shared__ float srow[64];
  __shared__ float bo[256];
  __shared__ float part[4][64];
  __shared__ float ysc[64];

  if (tid < 64) srow[tid] = rsqrtf(sumsq[(size_t)t*64 + tid] + 1e-12f);
  bo[tid] = b_out[tid];
  __syncthreads();

  f32x4 acc[4][4];
  #pragma unroll
  for (int mt = 0; mt < 4; mt++)
    #pragma unroll
    for (int nt = 0; nt < 4; nt++) acc[mt][nt] = (f32x4){0.f,0.f,0.f,0.f};

  const unsigned short* arow[4];
  const unsigned short* brow[4];
  #pragma unroll
  for (int mt = 0; mt < 4; mt++)
    arow[mt] = hs + ((size_t)t*4 + mt)*8192 + lm*32 + quad*8;
  #pragma unroll
  for (int nt = 0; nt < 4; nt++)
    brow[nt] = wob + ((size_t)(wave*64 + nt*16 + lm))*512 + quad*8;

  #pragma unroll 2
  for (int k = 0; k < 16; k++){
    short8x a[4], b[4];
    #pragma unroll
    for (int mt = 0; mt < 4; mt++) a[mt] = *(const short8x*)(arow[mt] + (size_t)k*512);
    #pragma unroll
    for (int nt = 0; nt < 4; nt++) b[nt] = *(const short8x*)(brow[nt] + k*32);
    #pragma unroll
    for (int mt = 0; mt < 4; mt++)
      #pragma unroll
      for (int nt = 0; nt < 4; nt++) acc[mt][nt] = MFMA(a[mt], b[nt], acc[mt][nt]);
  }

  float loc[4][4];
  #pragma unroll
  for (int mt = 0; mt < 4; mt++)
    #pragma unroll
    for (int r = 0; r < 4; r++) loc[mt][r] = 0.f;
  #pragma unroll
  for (int mt = 0; mt < 4; mt++){
    #pragma unroll
    for (int nt = 0; nt < 4; nt++){
      f32x4 v = acc[mt][nt];
      #pragma unroll
      for (int r = 0; r < 4; r++){
        int row = mt*16 + quad*4 + r;
        float y = srow[row]*v[r] + bo[wave*64 + nt*16 + lm];
        v[r] = y;
        loc[mt][r] += y*y;
      }
      acc[mt][nt] = v;
    }
  }
  #pragma unroll
  for (int off = 8; off; off >>= 1){
    #pragma unroll
    for (int mt = 0; mt < 4; mt++)
      #pragma unroll
      for (int r = 0; r < 4; r++) loc[mt][r] += __shfl_xor(loc[mt][r], off, 16);
  }
  if (lm == 0){
    #pragma unroll
    for (int mt = 0; mt < 4; mt++)
      #pragma unroll
      for (int r = 0; r < 4; r++) part[wave][mt*16 + quad*4 + r] = loc[mt][r];
  }
  __syncthreads();
  if (tid < 64) ysc[tid] = rsqrtf(part[0][tid] + part[1][tid] + part[2][tid] + part[3][tid] + 1e-12f);
  __syncthreads();

  #pragma unroll
  for (int mt = 0; mt < 4; mt++){
    #pragma unroll
    for (int nt = 0; nt < 4; nt++){
      #pragma unroll
      for (int r = 0; r < 4; r++){
        int row = mt*16 + quad*4 + r;
        int o   = wave*64 + nt*16 + lm;
        out[((size_t)row * T_ + t) * O_ + o] = acc[mt][nt][r] * ysc[row];
      }
    }
  }
}

// ---------------------------------------------------------------------------
extern "C" void kernel_launch(void* const* d_in, const int* in_sizes, int n_in,
                              void* d_out, int out_size, void* d_ws, size_t ws_size,
                              hipStream_t stream)
{
  (void)in_sizes; (void)n_in; (void)out_size;
  const float* cv   = (const float*)d_in[0];
  const float* w0   = (const float*)d_in[1];
  const float* b0v  = (const float*)d_in[2];
  const float* w1   = (const float*)d_in[3];
  const float* b1v  = (const float*)d_in[4];
  const float* w2   = (const float*)d_in[5];
  const float* b2v  = (const float*)d_in[6];
  const float* wih  = (const float*)d_in[7];
  const float* whh  = (const float*)d_in[8];
  const float* bg   = (const float*)d_in[9];
  const float* bn   = (const float*)d_in[10];
  const float* wout = (const float*)d_in[11];
  const float* bout = (const float*)d_in[12];
  float* out = (float*)d_out;

  // workspace layout
  const size_t HS_BYTES  = (size_t)T_ * B_ * H_ * 2;        // bf16 pre-retract h
  const size_t SS_BYTES  = (size_t)T_ * B_ * 4;
  const size_t OFF_SS    = HS_BYTES;
  const size_t OFF_WOB   = OFF_SS + SS_BYTES;
  const size_t NEED      = OFF_WOB + (size_t)O_ * H_ * 2;
  if (ws_size < NEED) return;

  unsigned short* hs    = (unsigned short*)d_ws;
  float*          sumsq = (float*)((char*)d_ws + OFF_SS);
  unsigned short* wob   = (unsigned short*)((char*)d_ws + OFF_WOB);

  // sentinel prefill of hs[t>=1]: 0xFFFF bf16 (-NaN), unreachable from finite math
  const size_t T0_BYTES = (size_t)4 * 8192 * 2;
  hipMemsetAsync((char*)d_ws + T0_BYTES, 0xFF, HS_BYTES - T0_BYTES, stream);

  hipLaunchKernelGGL(k_mlp,   dim3(64),   dim3(256), 0, stream,
                     cv, w0, b0v, w1, b1v, w2, b2v, hs);
  hipLaunchKernelGGL(k_wcvt,  dim3(512),  dim3(256), 0, stream, wout, wob);
  hipLaunchKernelGGL(k_scan,  dim3(64),   dim3(256), 0, stream,
                     cv, wih, whh, bg, bn, hs, sumsq);
  hipLaunchKernelGGL(k_ygemm, dim3(2048), dim3(256), 0, stream,
                     hs, sumsq, wob, bout, out);
}

// Round 9
// 7624.117 us; speedup vs baseline: 2.4866x; 1.0240x over previous
//
#include <hip/hip_runtime.h>
#include <math.h>

#define B_  64
#define T_  2048
#define C_  256
#define H_  512
#define O_  256
#define NSTEP 2047

typedef __attribute__((ext_vector_type(8))) short short8x;
typedef __attribute__((ext_vector_type(4))) float f32x4;

__device__ __forceinline__ unsigned short f2bf_bits(float x){
  unsigned int u = __builtin_bit_cast(unsigned int, x);
  u = u + 0x7FFFu + ((u >> 16) & 1u);      // RNE
  return (unsigned short)(u >> 16);
}
__device__ __forceinline__ float bf2f(unsigned short h){
  unsigned int u = ((unsigned int)h) << 16;
  return __builtin_bit_cast(float, u);
}
__device__ __forceinline__ short8x pack8(float4 a, float4 b){
  short8x w;
  w[0]=(short)f2bf_bits(a.x); w[1]=(short)f2bf_bits(a.y);
  w[2]=(short)f2bf_bits(a.z); w[3]=(short)f2bf_bits(a.w);
  w[4]=(short)f2bf_bits(b.x); w[5]=(short)f2bf_bits(b.y);
  w[6]=(short)f2bf_bits(b.z); w[7]=(short)f2bf_bits(b.w);
  return w;
}
__device__ __forceinline__ f32x4 MFMA(short8x a, short8x b, f32x4 c){
  return __builtin_amdgcn_mfma_f32_16x16x32_bf16(a, b, c, 0, 0, 0);
}
__device__ __forceinline__ float softplus_f(float x){
  return (x > 20.f) ? x : log1pf(expf(x));
}
__device__ __forceinline__ float fast_exp2(float x){ return __builtin_amdgcn_exp2f(x); }
__device__ __forceinline__ float fast_rcp(float x){ return __builtin_amdgcn_rcpf(x); }
__device__ __forceinline__ float sigmoid_f(float x){
  return fast_rcp(1.f + fast_exp2(-1.44269504f * x));
}
__device__ __forceinline__ float tanh_f(float x){
  return 1.f - 2.f * fast_rcp(1.f + fast_exp2(2.88539008f * x));
}

// agent-scope ops: bypass stale L1/L2, hit the device coherence point (LLC).
__device__ __forceinline__ void st_agent_u64(unsigned long long* p, unsigned long long v){
  __hip_atomic_store(p, v, __ATOMIC_RELAXED, __HIP_MEMORY_SCOPE_AGENT);
}
__device__ __forceinline__ unsigned long long ld_agent_u64(unsigned long long* p){
  return __hip_atomic_load(p, __ATOMIC_RELAXED, __HIP_MEMORY_SCOPE_AGENT);
}

// any 16-bit field == 0xFFFF (sentinel = -NaN bf16, unreachable from finite math)
__device__ __forceinline__ int has_ffff(unsigned long long w){
  unsigned long long nv = ~w;
  return ((nv - 0x0001000100010001ull) & ~nv & 0x8000800080008000ull) != 0ull;
}
__device__ __forceinline__ float sq4(unsigned long long w){
  unsigned lo = (unsigned)w, hi = (unsigned)(w >> 32);
  float f0 = __builtin_bit_cast(float, lo << 16);
  float f1 = __builtin_bit_cast(float, lo & 0xFFFF0000u);
  float f2 = __builtin_bit_cast(float, hi << 16);
  float f3 = __builtin_bit_cast(float, hi & 0xFFFF0000u);
  return f0*f0 + f1*f1 + f2*f2 + f3*f3;
}

union ChunkU { short8x v; unsigned long long q[2]; };

// barrier with LDS-drain only (no vmcnt(0): do NOT serialize on store-ack)
__device__ __forceinline__ void barrier_lds(){
  asm volatile("s_waitcnt lgkmcnt(0)" ::: "memory");
  __builtin_amdgcn_s_barrier();
  asm volatile("" ::: "memory");
}

// hs layout: [t][g(4)][slice(16)][bb(16)][u(32)] bf16
// index(t,g,s,bb,u) = ((t*4+g)*8192) + s*512 + bb*32 + u   (in shorts)

// ---------------------------------------------------------------------------
// Init MLP -> hs[t=0] (pre-retract bf16).
// ---------------------------------------------------------------------------
__global__ void k_mlp(const float* __restrict__ cv,
                      const float* __restrict__ w0, const float* __restrict__ bb0,
                      const float* __restrict__ w1, const float* __restrict__ bb1,
                      const float* __restrict__ w2, const float* __restrict__ bb2,
                      unsigned short* __restrict__ hs)
{
  const int b = blockIdx.x, tid = threadIdx.x;
  const int wave = tid >> 6, lane = tid & 63;
  __shared__ float xr[256], a0[512], a1[512], a2[512];

  xr[tid] = cv[(size_t)b * T_ * C_ + tid];
  __syncthreads();

  for (int i = 0; i < 32; i++){
    float s[4];
    #pragma unroll
    for (int uu = 0; uu < 4; uu++){
      int j = wave*128 + i*4 + uu;
      const float4* wr = (const float4*)(w0 + (size_t)j * 256);
      float4 w = wr[lane];
      s[uu] = w.x*xr[lane*4+0] + w.y*xr[lane*4+1] + w.z*xr[lane*4+2] + w.w*xr[lane*4+3];
    }
    #pragma unroll
    for (int off = 32; off; off >>= 1){
      #pragma unroll
      for (int uu = 0; uu < 4; uu++) s[uu] += __shfl_xor(s[uu], off, 64);
    }
    if (lane < 4){ int j = wave*128 + i*4 + lane; a0[j] = softplus_f(s[lane] + bb0[j]); }
  }
  __syncthreads();

  for (int i = 0; i < 32; i++){
    float s[4];
    #pragma unroll
    for (int uu = 0; uu < 4; uu++){
      int j = wave*128 + i*4 + uu;
      const float4* wr = (const float4*)(w1 + (size_t)j * 512);
      float4 wA = wr[lane*2], wB = wr[lane*2+1];
      int k0 = lane*8;
      s[uu] = wA.x*a0[k0]   + wA.y*a0[k0+1] + wA.z*a0[k0+2] + wA.w*a0[k0+3]
            + wB.x*a0[k0+4] + wB.y*a0[k0+5] + wB.z*a0[k0+6] + wB.w*a0[k0+7];
    }
    #pragma unroll
    for (int off = 32; off; off >>= 1){
      #pragma unroll
      for (int uu = 0; uu < 4; uu++) s[uu] += __shfl_xor(s[uu], off, 64);
    }
    if (lane < 4){ int j = wave*128 + i*4 + lane; a1[j] = softplus_f(s[lane] + bb1[j]); }
  }
  __syncthreads();

  for (int i = 0; i < 32; i++){
    float s[4];
    #pragma unroll
    for (int uu = 0; uu < 4; uu++){
      int j = wave*128 + i*4 + uu;
      const float4* wr = (const float4*)(w2 + (size_t)j * 512);
      float4 wA = wr[lane*2], wB = wr[lane*2+1];
      int k0 = lane*8;
      s[uu] = wA.x*a1[k0]   + wA.y*a1[k0+1] + wA.z*a1[k0+2] + wA.w*a1[k0+3]
            + wB.x*a1[k0+4] + wB.y*a1[k0+5] + wB.z*a1[k0+6] + wB.w*a1[k0+7];
    }
    #pragma unroll
    for (int off = 32; off; off >>= 1){
      #pragma unroll
      for (int uu = 0; uu < 4; uu++) s[uu] += __shfl_xor(s[uu], off, 64);
    }
    if (lane < 4){ int j = wave*128 + i*4 + lane; a2[j] = s[lane] + bb2[j]; }
  }
  __syncthreads();

  const int g = b >> 4, bb = b & 15;
  {
    int u = tid;
    hs[(size_t)g*8192 + (u>>5)*512 + bb*32 + (u&31)] = f2bf_bits(a2[u]);
    u = tid + 256;
    hs[(size_t)g*8192 + (u>>5)*512 + bb*32 + (u&31)] = f2bf_bits(a2[u]);
  }
}

// ---------------------------------------------------------------------------
__global__ void k_wcvt(const float* __restrict__ w, unsigned short* __restrict__ o)
{
  int idx = blockIdx.x * 256 + threadIdx.x;
  if (idx < O_ * H_) o[idx] = f2bf_bits(w[idx]);
}

// ---------------------------------------------------------------------------
// Persistent GRU scan, v9 = r3 data path + packed u64 publish:
// gate-phase ownership remapped to (bb = tid>>4, uu = 2*(tid&15)+{0,1}) so
// each thread's two h values are address-consecutive; pack to u32, pair via
// one shfl_xor, even lanes issue ONE u64 agent store covering 4 units.
// 4x fewer store transactions; each consumer-validated u64 = ONE store
// (tail ~p instead of p^4). Published bytes/addresses identical to r3.
// 64 wgs = 4 batch-groups x 16 unit-slices.
// ---------------------------------------------------------------------------
__global__ __launch_bounds__(256, 1)
void k_scan(const float* __restrict__ cv, const float* __restrict__ w_ih,
            const float* __restrict__ w_hh, const float* __restrict__ bias,
            const float* __restrict__ b_n,
            unsigned short* __restrict__ hs, float* __restrict__ sumsq)
{
  const int wg   = blockIdx.x;
  const int g    = wg >> 4;         // batch group 0..3
  const int sidx = wg & 15;         // unit slice 0..15
  const int b0   = g * 16;
  const int u0   = sidx * 32;
  const int tid  = threadIdx.x;
  const int wave = tid >> 6, lane = tid & 63;
  const int lm   = lane & 15, quad = lane >> 4;

  // gate-phase ownership: consecutive units
  const int gbb  = tid >> 4;        // batch row 0..15
  const int gj   = tid & 15;        // unit-pair index
  const int guu  = 2 * gj;          // units guu, guu+1

  __shared__ float accLds[12][16][16];       // 0..5 hh (gate*2+nt), 6..11 ih
  __shared__ float ssqR[3][16];              // per-wave sumsq partials per batch
  __shared__ unsigned short tileOwn[512];    // own slice's h_{t-1} chunk (1 KiB)
  __shared__ float bias_lds[3][32];
  __shared__ float bn_lds[32];

  if (tid < 32){
    bias_lds[0][tid] = bias[u0 + tid];
    bias_lds[1][tid] = bias[512 + u0 + tid];
    bias_lds[2][tid] = bias[1024 + u0 + tid];
    bn_lds[tid]      = b_n[u0 + tid];
  }
  // own pre-retract h (fp32) in registers, consecutive-unit mapping
  float hp0 = bf2f(hs[(size_t)g*8192 + sidx*512 + gbb*32 + guu]);
  float hp1 = bf2f(hs[(size_t)g*8192 + sidx*512 + gbb*32 + guu + 1]);
  // stage own chunk of h_0 in LDS (consumed at t=1 phase A), packed u32
  {
    unsigned pk = (unsigned)f2bf_bits(hp0) | ((unsigned)f2bf_bits(hp1) << 16);
    *(unsigned*)&tileOwn[gbb*32 + guu] = pk;
  }

  // ---- weight fragments in registers (bf16), loaded once ----
  short8x wreg[48];
  if (wave < 3){
    const int gate = wave;
    #pragma unroll
    for (int nt = 0; nt < 2; nt++){
      #pragma unroll
      for (int k = 0; k < 16; k++){
        const float* p = w_hh + ((size_t)(gate*512 + u0 + nt*16 + lm)) * 512 + k*32 + quad*8;
        wreg[nt*16 + k] = pack8(*(const float4*)p, *(const float4*)(p + 4));
      }
    }
  } else {
    #pragma unroll
    for (int g2 = 0; g2 < 3; g2++){
      #pragma unroll
      for (int nt = 0; nt < 2; nt++){
        #pragma unroll
        for (int kk = 0; kk < 8; kk++){
          const float* p = w_ih + ((size_t)(g2*512 + u0 + nt*16 + lm)) * 256 + kk*32 + quad*8;
          wreg[(g2*2 + nt)*8 + kk] = pack8(*(const float4*)p, *(const float4*)(p + 4));
        }
      }
    }
  }
  __syncthreads();

  for (int t = 1; t <= NSTEP; t++){
    if (wave < 3){
      // ---- phase A: cached tile load + sentinel validation ----
      short8x ownv = *(const short8x*)&tileOwn[lm*32 + quad*8];
      const unsigned short* hb = hs + ((size_t)(t-1)*4 + g)*8192 + lm*32 + quad*8;
      ChunkU ch[16];
      #pragma unroll
      for (int k = 0; k < 16; k++){
        if (k == sidx) ch[k].v = ownv;
        else           ch[k].v = *(const short8x*)(hb + (size_t)k*512);
      }
      unsigned pend = 0xFFFFu & ~(1u << sidx);
      int spin = 0;
      for (;;){
        unsigned np = 0u;
        #pragma unroll
        for (int k = 0; k < 16; k++)
          if (((pend >> k) & 1u) && (has_ffff(ch[k].q[0]) | has_ffff(ch[k].q[1])))
            np |= 1u << k;
        if (!__any((int)np)) break;
        pend = np;
        if (spin++) __builtin_amdgcn_s_sleep(1);   // backoff: don't hammer the fabric
        #pragma unroll
        for (int k = 0; k < 16; k++)
          if ((pend >> k) & 1u){
            unsigned long long* p = (unsigned long long*)(hb + (size_t)k*512);
            ch[k].q[0] = ld_agent_u64(p);
            ch[k].q[1] = ld_agent_u64(p + 1);
          }
      }

      // ---- hh-GEMM from registers ----
      f32x4 acc0 = {0.f,0.f,0.f,0.f}, acc1 = {0.f,0.f,0.f,0.f};
      #pragma unroll
      for (int k = 0; k < 16; k++){
        acc0 = MFMA(ch[k].v, wreg[k],      acc0);
        acc1 = MFMA(ch[k].v, wreg[16 + k], acc1);
      }
      #pragma unroll
      for (int r = 0; r < 4; r++){
        accLds[wave*2 + 0][quad*4 + r][lm] = acc0[r];
        accLds[wave*2 + 1][quad*4 + r][lm] = acc1[r];
      }

      // ---- in-wave sumsq of h_{t-1} (k-ranges 6/5/5 across waves 0..2) ----
      const int klo = (wave == 0) ? 0 : (wave == 1 ? 6 : 11);
      const int khi = (wave == 0) ? 6 : (wave == 1 ? 11 : 16);
      float s = 0.f;
      #pragma unroll
      for (int k = 0; k < 16; k++){
        if (k >= klo && k < khi) s += sq4(ch[k].q[0]) + sq4(ch[k].q[1]);
      }
      s += __shfl_xor(s, 16, 64);   // reduce over the 4 quads of batch lm
      s += __shfl_xor(s, 32, 64);
      if (lane < 16) ssqR[wave][lane] = s;
    } else {
      // ---- ih GEMM (no cross-wg dependency) ----
      short8x af[8];
      const size_t xbase = ((size_t)(b0 + lm) * T_ + t) * C_;
      #pragma unroll
      for (int kk = 0; kk < 8; kk++){
        const float* xp = cv + xbase + kk*32 + quad*8;
        af[kk] = pack8(*(const float4*)xp, *(const float4*)(xp + 4));
      }
      f32x4 acc[6];
      #pragma unroll
      for (int tt = 0; tt < 6; tt++) acc[tt] = (f32x4){0.f,0.f,0.f,0.f};
      #pragma unroll
      for (int kk = 0; kk < 8; kk++){
        #pragma unroll
        for (int tt = 0; tt < 6; tt++) acc[tt] = MFMA(af[kk], wreg[tt*8 + kk], acc[tt]);
      }
      #pragma unroll
      for (int tt = 0; tt < 6; tt++){
        #pragma unroll
        for (int r = 0; r < 4; r++) accLds[6 + tt][quad*4 + r][lm] = acc[tt][r];
      }
    }
    barrier_lds();

    // ------- gate phase: thread owns (gbb, guu) and (gbb, guu+1) -------
    const float sB = ssqR[0][gbb] + ssqR[1][gbb] + ssqR[2][gbb];
    if (sidx == 0 && gj == 0)
      sumsq[(size_t)(t-1)*64 + b0 + gbb] = sB;
    const float sp = rsqrtf(sB + 1e-12f);
    float hn0, hn1;
    {
      const int uu = guu, nt = uu >> 4, ul = uu & 15;
      float rv = accLds[6 + 0 + nt][gbb][ul] + bias_lds[0][uu] + sp*accLds[0 + nt][gbb][ul];
      float zv = accLds[6 + 2 + nt][gbb][ul] + bias_lds[1][uu] + sp*accLds[2 + nt][gbb][ul];
      float nv = accLds[6 + 4 + nt][gbb][ul] + bias_lds[2][uu];
      float hh = sp*accLds[4 + nt][gbb][ul];
      float r  = sigmoid_f(rv);
      float z  = sigmoid_f(zv);
      float n  = tanh_f(nv + r*(hh + bn_lds[uu]));
      float hp = sp * hp0;
      hn0 = n + z*(hp - n);
      hp0 = hn0;
    }
    {
      const int uu = guu + 1, nt = uu >> 4, ul = uu & 15;
      float rv = accLds[6 + 0 + nt][gbb][ul] + bias_lds[0][uu] + sp*accLds[0 + nt][gbb][ul];
      float zv = accLds[6 + 2 + nt][gbb][ul] + bias_lds[1][uu] + sp*accLds[2 + nt][gbb][ul];
      float nv = accLds[6 + 4 + nt][gbb][ul] + bias_lds[2][uu];
      float hh = sp*accLds[4 + nt][gbb][ul];
      float r  = sigmoid_f(rv);
      float z  = sigmoid_f(zv);
      float n  = tanh_f(nv + r*(hh + bn_lds[uu]));
      float hp = sp * hp1;
      hn1 = n + z*(hp - n);
      hp1 = hn1;
    }
    // pack 2 bf16 -> u32; own chunk into LDS (u32 write)
    unsigned pk = (unsigned)f2bf_bits(hn0) | ((unsigned)f2bf_bits(hn1) << 16);
    *(unsigned*)&tileOwn[gbb*32 + guu] = pk;
    // pair with neighbor lane -> ONE u64 agent store per even lane (4 units)
    {
      unsigned ok = __shfl_xor(pk, 1, 64);
      if (!(tid & 1)){
        unsigned long long val = (unsigned long long)pk | ((unsigned long long)ok << 32);
        st_agent_u64((unsigned long long*)(hs + ((size_t)t*4 + g)*8192 + sidx*512 + gbb*32 + guu), val);
      }
    }
    barrier_lds();   // lgkm drain only: global stores stay in flight
  }

  // epilogue: sumsq for t = NSTEP (one wave per group polls the final tile)
  if (sidx == 0 && wave == 0){
    unsigned long long* base =
      (unsigned long long*)(hs + ((size_t)NSTEP*4 + g)*8192 + lm*32 + quad*8);
    unsigned long long v0[16], v1[16];
    unsigned pend2 = 0xFFFFu;
    do {
      #pragma unroll
      for (int k = 0; k < 16; k++){
        if (pend2 & (1u<<k)){
          v0[k] = ld_agent_u64(base + (size_t)k*128);
          v1[k] = ld_agent_u64(base + (size_t)k*128 + 1);
        }
      }
      unsigned np = 0u;
      #pragma unroll
      for (int k = 0; k < 16; k++){
        if ((pend2 & (1u<<k)) && (has_ffff(v0[k]) | has_ffff(v1[k]))) np |= (1u<<k);
      }
      pend2 = np;
    } while (__any((int)pend2));
    float s = 0.f;
    #pragma unroll
    for (int k = 0; k < 16; k++) s += sq4(v0[k]) + sq4(v1[k]);
    s += __shfl_xor(s, 16, 64);
    s += __shfl_xor(s, 32, 64);
    if (lane < 16) sumsq[(size_t)NSTEP*64 + b0 + lane] = s;
  }
}

// ---------------------------------------------------------------------------
// Output GEMM with fused retract. hs layout [t][g][slice][bb][u].
// ---------------------------------------------------------------------------
__global__ __launch_bounds__(256, 2)
void k_ygemm(const unsigned short* __restrict__ hs, const float* __restrict__ sumsq,
             const unsigned short* __restrict__ wob, const float* __restrict__ b_out,
             float* __restrict__ out)
{
  const int t = blockIdx.x;
  const int tid = threadIdx.x, wave = tid >> 6, lane = tid & 63;
  const int lm = lane & 15, quad = lane >> 4;
  __shared__ float srow[64];
  __shared__ float bo[256];
  __shared__ float part[4][64];
  __shared__ float ysc[64];

  if (tid < 64) srow[tid] = rsqrtf(sumsq[(size_t)t*64 + tid] + 1e-12f);
  bo[tid] = b_out[tid];
  __syncthreads();

  f32x4 acc[4][4];
  #pragma unroll
  for (int mt = 0; mt < 4; mt++)
    #pragma unroll
    for (int nt = 0; nt < 4; nt++) acc[mt][nt] = (f32x4){0.f,0.f,0.f,0.f};

  const unsigned short* arow[4];
  const unsigned short* brow[4];
  #pragma unroll
  for (int mt = 0; mt < 4; mt++)
    arow[mt] = hs + ((size_t)t*4 + mt)*8192 + lm*32 + quad*8;
  #pragma unroll
  for (int nt = 0; nt < 4; nt++)
    brow[nt] = wob + ((size_t)(wave*64 + nt*16 + lm))*512 + quad*8;

  #pragma unroll 2
  for (int k = 0; k < 16; k++){
    short8x a[4], b[4];
    #pragma unroll
    for (int mt = 0; mt < 4; mt++) a[mt] = *(const short8x*)(arow[mt] + (size_t)k*512);
    #pragma unroll
    for (int nt = 0; nt < 4; nt++) b[nt] = *(const short8x*)(brow[nt] + k*32);
    #pragma unroll
    for (int mt = 0; mt < 4; mt++)
      #pragma unroll
      for (int nt = 0; nt < 4; nt++) acc[mt][nt] = MFMA(a[mt], b[nt], acc[mt][nt]);
  }

  float loc[4][4];
  #pragma unroll
  for (int mt = 0; mt < 4; mt++)
    #pragma unroll
    for (int r = 0; r < 4; r++) loc[mt][r] = 0.f;
  #pragma unroll
  for (int mt = 0; mt < 4; mt++){
    #pragma unroll
    for (int nt = 0; nt < 4; nt++){
      f32x4 v = acc[mt][nt];
      #pragma unroll
      for (int r = 0; r < 4; r++){
        int row = mt*16 + quad*4 + r;
        float y = srow[row]*v[r] + bo[wave*64 + nt*16 + lm];
        v[r] = y;
        loc[mt][r] += y*y;
      }
      acc[mt][nt] = v;
    }
  }
  #pragma unroll
  for (int off = 8; off; off >>= 1){
    #pragma unroll
    for (int mt = 0; mt < 4; mt++)
      #pragma unroll
      for (int r = 0; r < 4; r++) loc[mt][r] += __shfl_xor(loc[mt][r], off, 16);
  }
  if (lm == 0){
    #pragma unroll
    for (int mt = 0; mt < 4; mt++)
      #pragma unroll
      for (int r = 0; r < 4; r++) part[wave][mt*16 + quad*4 + r] = loc[mt][r];
  }
  __syncthreads();
  if (tid < 64) ysc[tid] = rsqrtf(part[0][tid] + part[1][tid] + part[2][tid] + part[3][tid] + 1e-12f);
  __syncthreads();

  #pragma unroll
  for (int mt = 0; mt < 4; mt++){
    #pragma unroll
    for (int nt = 0; nt < 4; nt++){
      #pragma unroll
      for (int r = 0; r < 4; r++){
        int row = mt*16 + quad*4 + r;
        int o   = wave*64 + nt*16 + lm;
        out[((size_t)row * T_ + t) * O_ + o] = acc[mt][nt][r] * ysc[row];
      }
    }
  }
}

// ---------------------------------------------------------------------------
extern "C" void kernel_launch(void* const* d_in, const int* in_sizes, int n_in,
                              void* d_out, int out_size, void* d_ws, size_t ws_size,
                              hipStream_t stream)
{
  (void)in_sizes; (void)n_in; (void)out_size;
  const float* cv   = (const float*)d_in[0];
  const float* w0   = (const float*)d_in[1];
  const float* b0v  = (const float*)d_in[2];
  const float* w1   = (const float*)d_in[3];
  const float* b1v  = (const float*)d_in[4];
  const float* w2   = (const float*)d_in[5];
  const float* b2v  = (const float*)d_in[6];
  const float* wih  = (const float*)d_in[7];
  const float* whh  = (const float*)d_in[8];
  const float* bg   = (const float*)d_in[9];
  const float* bn   = (const float*)d_in[10];
  const float* wout = (const float*)d_in[11];
  const float* bout = (const float*)d_in[12];
  float* out = (float*)d_out;

  // workspace layout
  const size_t HS_BYTES  = (size_t)T_ * B_ * H_ * 2;        // bf16 pre-retract h
  const size_t SS_BYTES  = (size_t)T_ * B_ * 4;
  const size_t OFF_SS    = HS_BYTES;
  const size_t OFF_WOB   = OFF_SS + SS_BYTES;
  const size_t NEED      = OFF_WOB + (size_t)O_ * H_ * 2;
  if (ws_size < NEED) return;

  unsigned short* hs    = (unsigned short*)d_ws;
  float*          sumsq = (float*)((char*)d_ws + OFF_SS);
  unsigned short* wob   = (unsigned short*)((char*)d_ws + OFF_WOB);

  // sentinel prefill of hs[t>=1]: 0xFFFF bf16 (-NaN), unreachable from finite math
  const size_t T0_BYTES = (size_t)4 * 8192 * 2;
  hipMemsetAsync((char*)d_ws + T0_BYTES, 0xFF, HS_BYTES - T0_BYTES, stream);

  hipLaunchKernelGGL(k_mlp,   dim3(64),   dim3(256), 0, stream,
                     cv, w0, b0v, w1, b1v, w2, b2v, hs);
  hipLaunchKernelGGL(k_wcvt,  dim3(512),  dim3(256), 0, stream, wout, wob);
  hipLaunchKernelGGL(k_scan,  dim3(64),   dim3(256), 0, stream,
                     cv, wih, whh, bg, bn, hs, sumsq);
  hipLaunchKernelGGL(k_ygemm, dim3(2048), dim3(256), 0, stream,
                     hs, sumsq, wob, bout, out);
}